// Round 2
// baseline (2643.307 us; speedup 1.0000x reference)
//
#include <hip/hip_runtime.h>
#include <hip/hip_bf16.h>

// Network dims (fixed by the reference)
#define MTOT 16384      // B*T = 32*512 tokens; whole net is per-token
#define DMODEL 512
#define DI_ 1024
#define NLAYER 2

__device__ __forceinline__ float silu_f(float x) { return x / (1.0f + expf(-x)); }
__device__ __forceinline__ float softplus_f(float x) {
    return fmaxf(x, 0.0f) + log1pf(expf(-fabsf(x)));
}

// ---------------------------------------------------------------------------
// Generic NT GEMM: C[M,N] = epi(A[M,K] @ W[N,K]^T + bias[N])
// 128x128 tile, BK=8, 256 threads, 8x8 per thread.
// EPI: 0 = none, 1 = relu, 2 = in_w split epilogue
// ---------------------------------------------------------------------------
template <int EPI>
__global__ __launch_bounds__(256) void gemm128_k(
    const float* __restrict__ A, const float* __restrict__ W,
    const float* __restrict__ bias, float* __restrict__ C,
    int M, int N, int K,
    const float* __restrict__ cwf, const float* __restrict__ cbf,
    const float* __restrict__ cwb, const float* __restrict__ cbb,
    float* __restrict__ out2, float* __restrict__ out3)
{
    __shared__ float As[8][128];
    __shared__ float Ws[8][128];
    const int tid = threadIdx.x;
    const int tx = tid & 15, ty = tid >> 4;
    const int m0 = blockIdx.y * 128, n0 = blockIdx.x * 128;
    const int lrow = tid >> 1;          // 0..127
    const int lseg = (tid & 1) * 4;     // 0 or 4
    const float* Aptr = A + (size_t)(m0 + lrow) * K + lseg;
    const float* Wptr = W + (size_t)(n0 + lrow) * K + lseg;

    float acc[8][8];
#pragma unroll
    for (int i = 0; i < 8; ++i)
#pragma unroll
        for (int j = 0; j < 8; ++j) acc[i][j] = 0.0f;

    for (int k0 = 0; k0 < K; k0 += 8) {
        float4 av = *(const float4*)(Aptr + k0);
        float4 wv = *(const float4*)(Wptr + k0);
        __syncthreads();   // protect previous iteration's LDS reads
        As[lseg + 0][lrow] = av.x; As[lseg + 1][lrow] = av.y;
        As[lseg + 2][lrow] = av.z; As[lseg + 3][lrow] = av.w;
        Ws[lseg + 0][lrow] = wv.x; Ws[lseg + 1][lrow] = wv.y;
        Ws[lseg + 2][lrow] = wv.z; Ws[lseg + 3][lrow] = wv.w;
        __syncthreads();
#pragma unroll
        for (int k = 0; k < 8; ++k) {
            float a[8], b[8];
            *(float4*)(a)     = *(const float4*)&As[k][ty * 8];
            *(float4*)(a + 4) = *(const float4*)&As[k][ty * 8 + 4];
            *(float4*)(b)     = *(const float4*)&Ws[k][tx * 8];
            *(float4*)(b + 4) = *(const float4*)&Ws[k][tx * 8 + 4];
#pragma unroll
            for (int i = 0; i < 8; ++i)
#pragma unroll
                for (int j = 0; j < 8; ++j)
                    acc[i][j] = fmaf(a[i], b[j], acc[i][j]);
        }
    }

#pragma unroll
    for (int i = 0; i < 8; ++i) {
        const int r = m0 + ty * 8 + i;
#pragma unroll
        for (int j = 0; j < 8; ++j) {
            const int c = n0 + tx * 8 + j;
            float v = acc[i][j] + bias[c];
            if (EPI == 0) {
                C[(size_t)r * N + c] = v;
            } else if (EPI == 1) {
                C[(size_t)r * N + c] = fmaxf(v, 0.0f);
            } else {
                if (c < DI_) {
                    C[(size_t)r * DI_ + c]    = silu_f(v * cwf[c * 4 + 3] + cbf[c]);
                    out2[(size_t)r * DI_ + c] = silu_f(v * cwb[c * 4 + 3] + cbb[c]);
                } else {
                    out3[(size_t)r * DI_ + (c - DI_)] = silu_f(v);
                }
            }
        }
    }
}

// ---------------------------------------------------------------------------
// dbl = xc[M,K=1024] @ xproj[64,1024]^T  (no bias).  64x64 tile, BK=16.
// ---------------------------------------------------------------------------
__global__ __launch_bounds__(256) void gemm_dbl_k(
    const float* __restrict__ A, const float* __restrict__ W,
    float* __restrict__ C, int M, int K)
{
    __shared__ float As[16][64];
    __shared__ float Ws[16][64];
    const int tid = threadIdx.x;
    const int tx = tid & 15, ty = tid >> 4;
    const int m0 = blockIdx.x * 64;
    const int lrow = tid >> 2;        // 0..63
    const int lseg = (tid & 3) * 4;   // 0,4,8,12
    const float* Aptr = A + (size_t)(m0 + lrow) * K + lseg;
    const float* Wptr = W + (size_t)lrow * K + lseg;
    float acc[4][4];
#pragma unroll
    for (int i = 0; i < 4; ++i)
#pragma unroll
        for (int j = 0; j < 4; ++j) acc[i][j] = 0.0f;

    for (int k0 = 0; k0 < K; k0 += 16) {
        float4 av = *(const float4*)(Aptr + k0);
        float4 wv = *(const float4*)(Wptr + k0);
        __syncthreads();
        As[lseg + 0][lrow] = av.x; As[lseg + 1][lrow] = av.y;
        As[lseg + 2][lrow] = av.z; As[lseg + 3][lrow] = av.w;
        Ws[lseg + 0][lrow] = wv.x; Ws[lseg + 1][lrow] = wv.y;
        Ws[lseg + 2][lrow] = wv.z; Ws[lseg + 3][lrow] = wv.w;
        __syncthreads();
#pragma unroll
        for (int k = 0; k < 16; ++k) {
            float a[4], b[4];
            *(float4*)a = *(const float4*)&As[k][ty * 4];
            *(float4*)b = *(const float4*)&Ws[k][tx * 4];
#pragma unroll
            for (int i = 0; i < 4; ++i)
#pragma unroll
                for (int j = 0; j < 4; ++j)
                    acc[i][j] = fmaf(a[i], b[j], acc[i][j]);
        }
    }
#pragma unroll
    for (int i = 0; i < 4; ++i) {
        const int r = m0 + ty * 4 + i;
        float4 v = make_float4(acc[i][0], acc[i][1], acc[i][2], acc[i][3]);
        *(float4*)&C[(size_t)r * 64 + tx * 4] = v;
    }
}

// ---------------------------------------------------------------------------
// bc[r] = sum_{s<16} dbl[r,32+s]*dbl[r,48+s] for fwd and bwd. 16 rows/block.
// ---------------------------------------------------------------------------
__global__ __launch_bounds__(256) void bc_k(
    const float* __restrict__ dblf, const float* __restrict__ dblb,
    float* __restrict__ bcf, float* __restrict__ bcb)
{
    const int tid = threadIdx.x;
    const int g = tid >> 4, s = tid & 15;
    const int row = blockIdx.x * 16 + g;
    float pf = dblf[(size_t)row * 64 + 32 + s] * dblf[(size_t)row * 64 + 48 + s];
    float pb = dblb[(size_t)row * 64 + 32 + s] * dblb[(size_t)row * 64 + 48 + s];
#pragma unroll
    for (int m = 8; m >= 1; m >>= 1) {
        pf += __shfl_xor(pf, m, 64);
        pb += __shfl_xor(pb, m, 64);
    }
    if (s == 0) { bcf[row] = pf; bcb[row] = pb; }
}

// ---------------------------------------------------------------------------
// Fused dt GEMM (K=32) for fwd+bwd plus full SSM epilogue:
//   y = (xcf*(softplus(dtf)*bcf + Dpf) + xcb*(softplus(dtb)*bcb + Dpb)) * sz
// sz and y may ALIAS (in-place): each element read once then overwritten by
// the same thread. 64x64 tile, grid (1024/64, M/64)
// ---------------------------------------------------------------------------
__global__ __launch_bounds__(256) void gemm_dty_k(
    const float* __restrict__ dblf, const float* __restrict__ dblb,
    const float* __restrict__ Wf, const float* __restrict__ Wb,
    const float* __restrict__ dbf, const float* __restrict__ dbb,
    const float* __restrict__ Dpf, const float* __restrict__ Dpb,
    const float* __restrict__ bcf, const float* __restrict__ bcb,
    const float* __restrict__ xcf, const float* __restrict__ xcb,
    const float* sz, float* y)
{
    __shared__ float Af[32][64], Ab[32][64], Wfs[32][64], Wbs[32][64];
    const int tid = threadIdx.x;
    const int tx = tid & 15, ty = tid >> 4;
    const int m0 = blockIdx.y * 64, n0 = blockIdx.x * 64;
    const int lrow = tid >> 2;        // 0..63
    const int lk = (tid & 3) * 8;     // 0,8,16,24

    {   // single-shot load (K=32): dt_in is dbl cols 0..31 (row stride 64)
        float4 a0 = *(const float4*)(dblf + (size_t)(m0 + lrow) * 64 + lk);
        float4 a1 = *(const float4*)(dblf + (size_t)(m0 + lrow) * 64 + lk + 4);
        float4 b0 = *(const float4*)(dblb + (size_t)(m0 + lrow) * 64 + lk);
        float4 b1 = *(const float4*)(dblb + (size_t)(m0 + lrow) * 64 + lk + 4);
        float4 w0 = *(const float4*)(Wf + (size_t)(n0 + lrow) * 32 + lk);
        float4 w1 = *(const float4*)(Wf + (size_t)(n0 + lrow) * 32 + lk + 4);
        float4 x0 = *(const float4*)(Wb + (size_t)(n0 + lrow) * 32 + lk);
        float4 x1 = *(const float4*)(Wb + (size_t)(n0 + lrow) * 32 + lk + 4);
        Af[lk + 0][lrow] = a0.x; Af[lk + 1][lrow] = a0.y; Af[lk + 2][lrow] = a0.z; Af[lk + 3][lrow] = a0.w;
        Af[lk + 4][lrow] = a1.x; Af[lk + 5][lrow] = a1.y; Af[lk + 6][lrow] = a1.z; Af[lk + 7][lrow] = a1.w;
        Ab[lk + 0][lrow] = b0.x; Ab[lk + 1][lrow] = b0.y; Ab[lk + 2][lrow] = b0.z; Ab[lk + 3][lrow] = b0.w;
        Ab[lk + 4][lrow] = b1.x; Ab[lk + 5][lrow] = b1.y; Ab[lk + 6][lrow] = b1.z; Ab[lk + 7][lrow] = b1.w;
        Wfs[lk + 0][lrow] = w0.x; Wfs[lk + 1][lrow] = w0.y; Wfs[lk + 2][lrow] = w0.z; Wfs[lk + 3][lrow] = w0.w;
        Wfs[lk + 4][lrow] = w1.x; Wfs[lk + 5][lrow] = w1.y; Wfs[lk + 6][lrow] = w1.z; Wfs[lk + 7][lrow] = w1.w;
        Wbs[lk + 0][lrow] = x0.x; Wbs[lk + 1][lrow] = x0.y; Wbs[lk + 2][lrow] = x0.z; Wbs[lk + 3][lrow] = x0.w;
        Wbs[lk + 4][lrow] = x1.x; Wbs[lk + 5][lrow] = x1.y; Wbs[lk + 6][lrow] = x1.z; Wbs[lk + 7][lrow] = x1.w;
        __syncthreads();
    }

    float accf[4][4], accb[4][4];
#pragma unroll
    for (int i = 0; i < 4; ++i)
#pragma unroll
        for (int j = 0; j < 4; ++j) { accf[i][j] = 0.0f; accb[i][j] = 0.0f; }

#pragma unroll
    for (int k = 0; k < 32; ++k) {
        float af[4], bf[4], ab_[4], bb[4];
        *(float4*)af  = *(const float4*)&Af[k][ty * 4];
        *(float4*)ab_ = *(const float4*)&Ab[k][ty * 4];
        *(float4*)bf  = *(const float4*)&Wfs[k][tx * 4];
        *(float4*)bb  = *(const float4*)&Wbs[k][tx * 4];
#pragma unroll
        for (int i = 0; i < 4; ++i)
#pragma unroll
            for (int j = 0; j < 4; ++j) {
                accf[i][j] = fmaf(af[i], bf[j], accf[i][j]);
                accb[i][j] = fmaf(ab_[i], bb[j], accb[i][j]);
            }
    }

#pragma unroll
    for (int i = 0; i < 4; ++i) {
        const int r = m0 + ty * 4 + i;
        const float vbcf = bcf[r], vbcb = bcb[r];
#pragma unroll
        for (int j = 0; j < 4; ++j) {
            const int c = n0 + tx * 4 + j;
            const float dtf = softplus_f(accf[i][j] + dbf[c]);
            const float dtb = softplus_f(accb[i][j] + dbb[c]);
            const float vf = xcf[(size_t)r * DI_ + c] * (dtf * vbcf + Dpf[c]);
            const float vb = xcb[(size_t)r * DI_ + c] * (dtb * vbcb + Dpb[c]);
            y[(size_t)r * DI_ + c] = (vf + vb) * sz[(size_t)r * DI_ + c];
        }
    }
}

// ---------------------------------------------------------------------------
// Modality fusion: one wave per token. norms -> softmax(3) -> normalized mix.
// ---------------------------------------------------------------------------
__global__ __launch_bounds__(64) void fuseh_k(
    const float* __restrict__ r0, const float* __restrict__ r1,
    const float* __restrict__ r2, float* __restrict__ h)
{
    const int t = blockIdx.x;
    const int lane = threadIdx.x;
    const float* p0 = r0 + (size_t)t * DMODEL;
    const float* p1 = r1 + (size_t)t * DMODEL;
    const float* p2 = r2 + (size_t)t * DMODEL;
    float v0[8], v1[8], v2[8];
    *(float4*)(v0)     = *(const float4*)(p0 + lane * 4);
    *(float4*)(v0 + 4) = *(const float4*)(p0 + 256 + lane * 4);
    *(float4*)(v1)     = *(const float4*)(p1 + lane * 4);
    *(float4*)(v1 + 4) = *(const float4*)(p1 + 256 + lane * 4);
    *(float4*)(v2)     = *(const float4*)(p2 + lane * 4);
    *(float4*)(v2 + 4) = *(const float4*)(p2 + 256 + lane * 4);
    float s0 = 0.f, s1 = 0.f, s2 = 0.f;
#pragma unroll
    for (int j = 0; j < 8; ++j) {
        s0 += v0[j] * v0[j]; s1 += v1[j] * v1[j]; s2 += v2[j] * v2[j];
    }
#pragma unroll
    for (int m = 32; m >= 1; m >>= 1) {
        s0 += __shfl_xor(s0, m, 64);
        s1 += __shfl_xor(s1, m, 64);
        s2 += __shfl_xor(s2, m, 64);
    }
    const float n0 = sqrtf(s0), n1 = sqrtf(s1), n2 = sqrtf(s2);
    const float mx = fmaxf(n0, fmaxf(n1, n2));
    const float e0 = expf(n0 - mx), e1 = expf(n1 - mx), e2 = expf(n2 - mx);
    const float inv = 1.0f / (e0 + e1 + e2);
    const float w0 = e0 * inv / fmaxf(n0, 1e-12f);
    const float w1 = e1 * inv / fmaxf(n1, 1e-12f);
    const float w2 = e2 * inv / fmaxf(n2, 1e-12f);
    float o[8];
#pragma unroll
    for (int j = 0; j < 8; ++j) o[j] = w0 * v0[j] + w1 * v1[j] + w2 * v2[j];
    float* hp = h + (size_t)t * DMODEL;
    *(float4*)(hp + lane * 4)       = *(float4*)(o);
    *(float4*)(hp + 256 + lane * 4) = *(float4*)(o + 4);
}

// ---------------------------------------------------------------------------
// Head: logits = tanh(hid @ fc2^T + b), log_softmax(2).
// OUTPUT IS FLOAT32 (reference output dtype).
// ---------------------------------------------------------------------------
__global__ __launch_bounds__(256) void head_k(
    const float* __restrict__ hid, const float* __restrict__ fc2w,
    const float* __restrict__ fc2b, float* __restrict__ out,
    int c0)
{
    const int tid = threadIdx.x;
    const int lane = tid & 63;
    const int t = blockIdx.x * 4 + (tid >> 6);
    const float* hp = hid + (size_t)t * 256;
    float4 hv = *(const float4*)(hp + lane * 4);
    float4 w0 = *(const float4*)(fc2w + lane * 4);
    float4 w1 = *(const float4*)(fc2w + 256 + lane * 4);
    float d0 = hv.x * w0.x + hv.y * w0.y + hv.z * w0.z + hv.w * w0.w;
    float d1 = hv.x * w1.x + hv.y * w1.y + hv.z * w1.z + hv.w * w1.w;
#pragma unroll
    for (int m = 32; m >= 1; m >>= 1) {
        d0 += __shfl_xor(d0, m, 64);
        d1 += __shfl_xor(d1, m, 64);
    }
    if (lane == 0) {
        const float l0 = tanhf(d0 + fc2b[0]);
        const float l1 = tanhf(d1 + fc2b[1]);
        const float mx = fmaxf(l0, l1);
        const float lse = mx + logf(expf(l0 - mx) + expf(l1 - mx));
        const size_t gt = (size_t)(c0 + t);
        out[gt * 2 + 0] = l0 - lse;
        out[gt * 2 + 1] = l1 - lse;
    }
}

// ---------------------------------------------------------------------------
extern "C" void kernel_launch(void* const* d_in, const int* in_sizes, int n_in,
                              void* d_out, int out_size, void* d_ws, size_t ws_size,
                              hipStream_t stream)
{
    const float* text    = (const float*)d_in[0];
    const float* audio   = (const float*)d_in[1];
    // d_in[2] = beats: UNUSED by the reference
    const float* visual  = (const float*)d_in[3];
    const float* W_text  = (const float*)d_in[4];
    const float* b_text  = (const float*)d_in[5];
    const float* W_audio = (const float*)d_in[6];
    const float* b_audio = (const float*)d_in[7];
    const float* W_vis   = (const float*)d_in[8];
    const float* b_vis   = (const float*)d_in[9];
    const float* in_w    = (const float*)d_in[10];
    const float* in_b    = (const float*)d_in[11];
    const float* conv_w  = (const float*)d_in[12];
    const float* conv_b  = (const float*)d_in[13];
    const float* xproj_w = (const float*)d_in[14];
    const float* dt_w    = (const float*)d_in[15];
    const float* dt_b    = (const float*)d_in[16];
    const float* Dskip   = (const float*)d_in[17];
    const float* conv_wB = (const float*)d_in[18];
    const float* conv_bB = (const float*)d_in[19];
    const float* xprojB  = (const float*)d_in[20];
    const float* dt_wB   = (const float*)d_in[21];
    const float* dt_bB   = (const float*)d_in[22];
    const float* DskipB  = (const float*)d_in[23];
    const float* out_w   = (const float*)d_in[24];
    const float* out_b   = (const float*)d_in[25];
    const float* fc1_w   = (const float*)d_in[26];
    const float* fc1_b   = (const float*)d_in[27];
    const float* fc2_w   = (const float*)d_in[28];
    const float* fc2_b   = (const float*)d_in[29];
    float* out           = (float*)d_out;   // reference output dtype = float32

    // Per-token scratch floats: h 512 + xcf 1024 + xcb 1024 + szy 1024
    //                         + dbl 128 + bc 2 + hid 256 = 3970
    int Mc = MTOT;
    while ((size_t)Mc * 3970u * 4u > ws_size && Mc > 128) Mc >>= 1;

    float* ws     = (float*)d_ws;
    float* b_h    = ws;
    float* b_xcf  = b_h    + (size_t)Mc * 512;
    float* b_xcb  = b_xcf  + (size_t)Mc * 1024;
    float* b_szy  = b_xcb  + (size_t)Mc * 1024;   // silu(z), overwritten by y in-place
    float* b_dblf = b_szy  + (size_t)Mc * 1024;
    float* b_dblb = b_dblf + (size_t)Mc * 64;
    float* b_bcf  = b_dblb + (size_t)Mc * 64;
    float* b_bcb  = b_bcf  + Mc;
    float* b_hid  = b_bcb  + Mc;

    const dim3 blk(256);
    for (int c0 = 0; c0 < MTOT; c0 += Mc) {
        // modality projections (reps live in xcf/xcb/szy scratch)
        gemm128_k<1><<<dim3(4, Mc / 128), blk, 0, stream>>>(
            text + (size_t)c0 * 768, W_text, b_text, b_xcf, Mc, 512, 768,
            nullptr, nullptr, nullptr, nullptr, nullptr, nullptr);
        gemm128_k<1><<<dim3(4, Mc / 128), blk, 0, stream>>>(
            audio + (size_t)c0 * 512, W_audio, b_audio, b_xcb, Mc, 512, 512,
            nullptr, nullptr, nullptr, nullptr, nullptr, nullptr);
        gemm128_k<1><<<dim3(4, Mc / 128), blk, 0, stream>>>(
            visual + (size_t)c0 * 256, W_vis, b_vis, b_szy, Mc, 512, 256,
            nullptr, nullptr, nullptr, nullptr, nullptr, nullptr);
        fuseh_k<<<Mc, 64, 0, stream>>>(b_xcf, b_xcb, b_szy, b_h);

        for (int l = 0; l < NLAYER; ++l) {
            gemm128_k<2><<<dim3(16, Mc / 128), blk, 0, stream>>>(
                b_h, in_w + (size_t)l * 2048 * 512, in_b + l * 2048, b_xcf,
                Mc, 2048, 512,
                conv_w + l * 4096, conv_b + l * 1024,
                conv_wB + l * 4096, conv_bB + l * 1024, b_xcb, b_szy);
            gemm_dbl_k<<<Mc / 64, blk, 0, stream>>>(
                b_xcf, xproj_w + (size_t)l * 64 * 1024, b_dblf, Mc, 1024);
            gemm_dbl_k<<<Mc / 64, blk, 0, stream>>>(
                b_xcb, xprojB + (size_t)l * 64 * 1024, b_dblb, Mc, 1024);
            bc_k<<<Mc / 16, blk, 0, stream>>>(b_dblf, b_dblb, b_bcf, b_bcb);
            gemm_dty_k<<<dim3(16, Mc / 64), blk, 0, stream>>>(
                b_dblf, b_dblb,
                dt_w + (size_t)l * 1024 * 32, dt_wB + (size_t)l * 1024 * 32,
                dt_b + l * 1024, dt_bB + l * 1024,
                Dskip + l * 1024, DskipB + l * 1024,
                b_bcf, b_bcb, b_xcf, b_xcb, b_szy, b_szy);
            gemm128_k<0><<<dim3(4, Mc / 128), blk, 0, stream>>>(
                b_szy, out_w + (size_t)l * 512 * 1024, out_b + l * 512, b_h,
                Mc, 512, 1024,
                nullptr, nullptr, nullptr, nullptr, nullptr, nullptr);
        }

        gemm128_k<1><<<dim3(2, Mc / 128), blk, 0, stream>>>(
            b_h, fc1_w, fc1_b, b_hid, Mc, 256, 512,
            nullptr, nullptr, nullptr, nullptr, nullptr, nullptr);
        head_k<<<Mc / 4, blk, 0, stream>>>(b_hid, fc2_w, fc2_b, out, c0);
    }
}

// Round 3
// 1559.551 us; speedup vs baseline: 1.6949x; 1.6949x over previous
//
#include <hip/hip_runtime.h>
#include <hip/hip_bf16.h>

#define MTOT 16384      // B*T = 32*512 tokens; whole net is per-token
#define DI_ 1024

typedef __attribute__((ext_vector_type(8))) short bfrag;   // 8 bf16 (4 VGPR)
typedef __attribute__((ext_vector_type(4))) float ffrag;   // 4 f32 acc

typedef unsigned short ushort_t;

__device__ __forceinline__ float us2f(ushort_t u) {
    union { float f; unsigned int i; } c; c.i = ((unsigned int)u) << 16; return c.f;
}
__device__ __forceinline__ ushort_t f2us(float f) {
    __hip_bfloat16 b = __float2bfloat16(f);
    return *(ushort_t*)&b;
}
__device__ __forceinline__ float silu_f(float x) { return x / (1.0f + expf(-x)); }
__device__ __forceinline__ float softplus_f(float x) {
    return fmaxf(x, 0.0f) + log1pf(expf(-fabsf(x)));
}

// ---------------------------------------------------------------------------
// f32 -> bf16 conversion for 13 arrays in one launch (grid.y selects array)
// ---------------------------------------------------------------------------
struct CvtArgs {
    const float* src[13];
    ushort_t*    dst[13];
    int          n[13];
};
__global__ __launch_bounds__(256) void cvt_k(CvtArgs a)
{
    const int id = blockIdx.y;
    const int n4 = a.n[id] >> 2;
    const float* s = a.src[id];
    ushort_t* d = a.dst[id];
    const int stride = gridDim.x * blockDim.x;
    for (int i = blockIdx.x * blockDim.x + threadIdx.x; i < n4; i += stride) {
        float4 v = *(const float4*)(s + (size_t)i * 4);
        ushort_t o[4] = { f2us(v.x), f2us(v.y), f2us(v.z), f2us(v.w) };
        *(uint2*)(d + (size_t)i * 4) = *(uint2*)o;
    }
}

// ---------------------------------------------------------------------------
// MFMA NT GEMM: C[M,N] = epi(A[M,K]bf16 @ W[N,K]bf16^T + bias)
// Tile: BM = WR*FM*16, BN = WC*FN*16, BK=32. 256 threads = 4 waves.
// Reg-staged LDS, row pad 32->40 elems (80B stride: conflict-free b128 reads).
// EPI: 0 = none (bias optional), 1 = relu, 2 = in_w split epilogue
// ---------------------------------------------------------------------------
template <int FM, int FN, int WR, int WC, int EPI>
__global__ __launch_bounds__(256) void mgemm_k(
    const ushort_t* __restrict__ A, int lda,
    const ushort_t* __restrict__ W, int ldw,
    const float* __restrict__ bias,
    ushort_t* __restrict__ C, int ldc, int K,
    const float* __restrict__ cwf, const float* __restrict__ cbf,
    const float* __restrict__ cwb, const float* __restrict__ cbb,
    ushort_t* __restrict__ out2, ushort_t* __restrict__ out3)
{
    constexpr int BM = WR * FM * 16;
    constexpr int BN = WC * FN * 16;
    constexpr int NSEG = (BM + BN) * 4 / 256;   // 16B segments per thread
    constexpr int LSTR = 40;                    // padded row stride (bf16 elems)

    __shared__ ushort_t As[BM * LSTR];
    __shared__ ushort_t Ws[BN * LSTR];

    const int tid = threadIdx.x;
    const int lane = tid & 63;
    const int w = tid >> 6;
    const int wr = w / WC, wc = w % WC;
    const int m0 = blockIdx.y * BM, n0 = blockIdx.x * BN;

    // staging descriptors
    const ushort_t* gp[NSEG];
    ushort_t* lp[NSEG];
#pragma unroll
    for (int q = 0; q < NSEG; ++q) {
        int s = tid * NSEG + q;
        int row = s >> 2;
        int sk = (s & 3) * 8;
        if (row < BM) {
            gp[q] = A + (size_t)(m0 + row) * lda + sk;
            lp[q] = As + row * LSTR + sk;
        } else {
            int wrow = row - BM;
            gp[q] = W + (size_t)(n0 + wrow) * ldw + sk;
            lp[q] = Ws + wrow * LSTR + sk;
        }
    }

    ffrag acc[FM][FN];
#pragma unroll
    for (int i = 0; i < FM; ++i)
#pragma unroll
        for (int j = 0; j < FN; ++j) acc[i][j] = (ffrag){0.f, 0.f, 0.f, 0.f};

    const int rbase = wr * FM * 16 + (lane & 15);
    const int cbase = wc * FN * 16 + (lane & 15);
    const int koff = (lane >> 4) * 8;

    uint4 rg[NSEG];
#pragma unroll
    for (int q = 0; q < NSEG; ++q) rg[q] = *(const uint4*)gp[q];

    const int NT = K >> 5;
    for (int t = 0; t < NT; ++t) {
        __syncthreads();
#pragma unroll
        for (int q = 0; q < NSEG; ++q) *(uint4*)lp[q] = rg[q];
        __syncthreads();
        if (t + 1 < NT) {
#pragma unroll
            for (int q = 0; q < NSEG; ++q)
                rg[q] = *(const uint4*)(gp[q] + (t + 1) * 32);
        }
        bfrag af[FM], bw[FN];
#pragma unroll
        for (int i = 0; i < FM; ++i)
            af[i] = *(const bfrag*)(As + (rbase + i * 16) * LSTR + koff);
#pragma unroll
        for (int j = 0; j < FN; ++j)
            bw[j] = *(const bfrag*)(Ws + (cbase + j * 16) * LSTR + koff);
#pragma unroll
        for (int i = 0; i < FM; ++i)
#pragma unroll
            for (int j = 0; j < FN; ++j)
                acc[i][j] = __builtin_amdgcn_mfma_f32_16x16x32_bf16(
                    af[i], bw[j], acc[i][j], 0, 0, 0);
    }

    // epilogue: C/D layout col=lane&15, row=(lane>>4)*4+reg  [m89-verified]
#pragma unroll
    for (int j = 0; j < FN; ++j) {
        const int col = n0 + wc * FN * 16 + j * 16 + (lane & 15);
        const float bz = bias ? bias[col] : 0.0f;
        float cw_f = 0.f, cb_f = 0.f, cw_b = 0.f, cb_b = 0.f;
        int c2 = 0;
        bool lo = true;
        if (EPI == 2) {
            lo = (col < DI_);
            if (lo) {
                cw_f = cwf[col * 4 + 3]; cb_f = cbf[col];
                cw_b = cwb[col * 4 + 3]; cb_b = cbb[col];
            } else {
                c2 = col - DI_;
            }
        }
#pragma unroll
        for (int i = 0; i < FM; ++i) {
            const int r0 = m0 + wr * FM * 16 + i * 16 + (lane >> 4) * 4;
#pragma unroll
            for (int r = 0; r < 4; ++r) {
                const float v = acc[i][j][r] + bz;
                const size_t rr = (size_t)(r0 + r);
                if (EPI == 0) {
                    C[rr * ldc + col] = f2us(v);
                } else if (EPI == 1) {
                    C[rr * ldc + col] = f2us(fmaxf(v, 0.0f));
                } else {
                    if (lo) {
                        C[rr * DI_ + col]    = f2us(silu_f(v * cw_f + cb_f));
                        out2[rr * DI_ + col] = f2us(silu_f(v * cw_b + cb_b));
                    } else {
                        out3[rr * DI_ + c2] = f2us(silu_f(v));
                    }
                }
            }
        }
    }
}

// ---------------------------------------------------------------------------
// bc[r] = sum_{s<16} dbl[r,32+s]*dbl[r,48+s] (fwd & bwd), dbl is bf16 [M,64]
// ---------------------------------------------------------------------------
__global__ __launch_bounds__(256) void bc_k(
    const ushort_t* __restrict__ dblf, const ushort_t* __restrict__ dblb,
    float* __restrict__ bcf, float* __restrict__ bcb)
{
    const int tid = threadIdx.x;
    const int g = tid >> 4, s = tid & 15;
    const int row = blockIdx.x * 16 + g;
    float pf = us2f(dblf[(size_t)row * 64 + 32 + s]) * us2f(dblf[(size_t)row * 64 + 48 + s]);
    float pb = us2f(dblb[(size_t)row * 64 + 32 + s]) * us2f(dblb[(size_t)row * 64 + 48 + s]);
#pragma unroll
    for (int m = 8; m >= 1; m >>= 1) {
        pf += __shfl_xor(pf, m, 64);
        pb += __shfl_xor(pb, m, 64);
    }
    if (s == 0) { bcf[row] = pf; bcb[row] = pb; }
}

// ---------------------------------------------------------------------------
// dt GEMM (K=32, fwd+bwd) + full SSM epilogue, no LDS (operands L2-resident).
// 4 waves, each 32 rows x 64 cols. grid = (1024/64, M/128).
//   y = (xcf*(softplus(dtf)*bcf + Dpf) + xcb*(softplus(dtb)*bcb + Dpb)) * sz
// szy read (sz) then overwritten (y) by the same lane.
// ---------------------------------------------------------------------------
__global__ __launch_bounds__(256) void dty_k(
    const ushort_t* __restrict__ dblf, const ushort_t* __restrict__ dblb,
    const ushort_t* __restrict__ wtf,  const ushort_t* __restrict__ wtb,
    const float* __restrict__ dbf, const float* __restrict__ dbb,
    const float* __restrict__ Dpf, const float* __restrict__ Dpb,
    const float* __restrict__ bcf, const float* __restrict__ bcb,
    const ushort_t* __restrict__ xcf, const ushort_t* __restrict__ xcb,
    ushort_t* szy)
{
    const int tid = threadIdx.x, lane = tid & 63, w = tid >> 6;
    const int m0 = blockIdx.y * 128, n0 = blockIdx.x * 64;
    const int koff = (lane >> 4) * 8;

    bfrag aF[2], aB[2], wF[4], wB[4];
#pragma unroll
    for (int i = 0; i < 2; ++i) {
        const int row = m0 + w * 32 + i * 16 + (lane & 15);
        aF[i] = *(const bfrag*)(dblf + (size_t)row * 64 + koff);
        aB[i] = *(const bfrag*)(dblb + (size_t)row * 64 + koff);
    }
#pragma unroll
    for (int j = 0; j < 4; ++j) {
        const int col = n0 + j * 16 + (lane & 15);
        wF[j] = *(const bfrag*)(wtf + (size_t)col * 32 + koff);
        wB[j] = *(const bfrag*)(wtb + (size_t)col * 32 + koff);
    }
    ffrag accF[2][4], accB[2][4];
#pragma unroll
    for (int i = 0; i < 2; ++i)
#pragma unroll
        for (int j = 0; j < 4; ++j) {
            ffrag z = (ffrag){0.f, 0.f, 0.f, 0.f};
            accF[i][j] = __builtin_amdgcn_mfma_f32_16x16x32_bf16(aF[i], wF[j], z, 0, 0, 0);
            z = (ffrag){0.f, 0.f, 0.f, 0.f};
            accB[i][j] = __builtin_amdgcn_mfma_f32_16x16x32_bf16(aB[i], wB[j], z, 0, 0, 0);
        }

#pragma unroll
    for (int j = 0; j < 4; ++j) {
        const int c = n0 + j * 16 + (lane & 15);
        const float dbf_c = dbf[c], dbb_c = dbb[c];
        const float Dpf_c = Dpf[c], Dpb_c = Dpb[c];
#pragma unroll
        for (int i = 0; i < 2; ++i) {
            const int r0 = m0 + w * 32 + i * 16 + (lane >> 4) * 4;
#pragma unroll
            for (int r = 0; r < 4; ++r) {
                const int rr = r0 + r;
                const float dtf = softplus_f(accF[i][j][r] + dbf_c);
                const float dtb = softplus_f(accB[i][j][r] + dbb_c);
                const size_t idx = (size_t)rr * DI_ + c;
                const float vf = us2f(xcf[idx]) * (dtf * bcf[rr] + Dpf_c);
                const float vb = us2f(xcb[idx]) * (dtb * bcb[rr] + Dpb_c);
                szy[idx] = f2us((vf + vb) * us2f(szy[idx]));
            }
        }
    }
}

// ---------------------------------------------------------------------------
// Modality fusion: one wave/token, bf16 in/out.
// ---------------------------------------------------------------------------
__global__ __launch_bounds__(64) void fuseh_k(
    const ushort_t* __restrict__ r0, const ushort_t* __restrict__ r1,
    const ushort_t* __restrict__ r2, ushort_t* __restrict__ h)
{
    const int t = blockIdx.x;
    const int lane = threadIdx.x;
    uint4 raw0 = *(const uint4*)(r0 + (size_t)t * 512 + lane * 8);
    uint4 raw1 = *(const uint4*)(r1 + (size_t)t * 512 + lane * 8);
    uint4 raw2 = *(const uint4*)(r2 + (size_t)t * 512 + lane * 8);
    const ushort_t* p0 = (const ushort_t*)&raw0;
    const ushort_t* p1 = (const ushort_t*)&raw1;
    const ushort_t* p2 = (const ushort_t*)&raw2;
    float v0[8], v1[8], v2[8];
    float s0 = 0.f, s1 = 0.f, s2 = 0.f;
#pragma unroll
    for (int j = 0; j < 8; ++j) {
        v0[j] = us2f(p0[j]); v1[j] = us2f(p1[j]); v2[j] = us2f(p2[j]);
        s0 += v0[j] * v0[j]; s1 += v1[j] * v1[j]; s2 += v2[j] * v2[j];
    }
#pragma unroll
    for (int m = 32; m >= 1; m >>= 1) {
        s0 += __shfl_xor(s0, m, 64);
        s1 += __shfl_xor(s1, m, 64);
        s2 += __shfl_xor(s2, m, 64);
    }
    const float n0 = sqrtf(s0), n1 = sqrtf(s1), n2 = sqrtf(s2);
    const float mx = fmaxf(n0, fmaxf(n1, n2));
    const float e0 = expf(n0 - mx), e1 = expf(n1 - mx), e2 = expf(n2 - mx);
    const float inv = 1.0f / (e0 + e1 + e2);
    const float w0 = e0 * inv / fmaxf(n0, 1e-12f);
    const float w1 = e1 * inv / fmaxf(n1, 1e-12f);
    const float w2 = e2 * inv / fmaxf(n2, 1e-12f);
    ushort_t o[8];
#pragma unroll
    for (int j = 0; j < 8; ++j)
        o[j] = f2us(w0 * v0[j] + w1 * v1[j] + w2 * v2[j]);
    *(uint4*)(h + (size_t)t * 512 + lane * 8) = *(uint4*)o;
}

// ---------------------------------------------------------------------------
// Head: logits = tanh(hid @ fc2^T + b), log_softmax(2). OUTPUT FLOAT32.
// ---------------------------------------------------------------------------
__global__ __launch_bounds__(256) void head_k(
    const ushort_t* __restrict__ hid, const float* __restrict__ fc2w,
    const float* __restrict__ fc2b, float* __restrict__ out)
{
    const int tid = threadIdx.x;
    const int lane = tid & 63;
    const int t = blockIdx.x * 4 + (tid >> 6);
    uint2 raw = *(const uint2*)(hid + (size_t)t * 256 + lane * 4);
    const ushort_t* hp = (const ushort_t*)&raw;
    float4 w0 = *(const float4*)(fc2w + lane * 4);
    float4 w1 = *(const float4*)(fc2w + 256 + lane * 4);
    float h0 = us2f(hp[0]), h1 = us2f(hp[1]), h2 = us2f(hp[2]), h3 = us2f(hp[3]);
    float d0 = h0 * w0.x + h1 * w0.y + h2 * w0.z + h3 * w0.w;
    float d1 = h0 * w1.x + h1 * w1.y + h2 * w1.z + h3 * w1.w;
#pragma unroll
    for (int m = 32; m >= 1; m >>= 1) {
        d0 += __shfl_xor(d0, m, 64);
        d1 += __shfl_xor(d1, m, 64);
    }
    if (lane == 0) {
        const float l0 = tanhf(d0 + fc2b[0]);
        const float l1 = tanhf(d1 + fc2b[1]);
        const float mx = fmaxf(l0, l1);
        const float lse = mx + logf(expf(l0 - mx) + expf(l1 - mx));
        out[(size_t)t * 2 + 0] = l0 - lse;
        out[(size_t)t * 2 + 1] = l1 - lse;
    }
}

// ---------------------------------------------------------------------------
extern "C" void kernel_launch(void* const* d_in, const int* in_sizes, int n_in,
                              void* d_out, int out_size, void* d_ws, size_t ws_size,
                              hipStream_t stream)
{
    const float* text    = (const float*)d_in[0];
    const float* audio   = (const float*)d_in[1];
    const float* visual  = (const float*)d_in[3];
    const float* W_text  = (const float*)d_in[4];
    const float* b_text  = (const float*)d_in[5];
    const float* W_audio = (const float*)d_in[6];
    const float* b_audio = (const float*)d_in[7];
    const float* W_vis   = (const float*)d_in[8];
    const float* b_vis   = (const float*)d_in[9];
    const float* in_w    = (const float*)d_in[10];
    const float* in_b    = (const float*)d_in[11];
    const float* conv_w  = (const float*)d_in[12];
    const float* conv_b  = (const float*)d_in[13];
    const float* xproj_w = (const float*)d_in[14];
    const float* dt_w    = (const float*)d_in[15];
    const float* dt_b    = (const float*)d_in[16];
    const float* Dskip   = (const float*)d_in[17];
    const float* conv_wB = (const float*)d_in[18];
    const float* conv_bB = (const float*)d_in[19];
    const float* xprojB  = (const float*)d_in[20];
    const float* dt_wB   = (const float*)d_in[21];
    const float* dt_bB   = (const float*)d_in[22];
    const float* DskipB  = (const float*)d_in[23];
    const float* out_w   = (const float*)d_in[24];
    const float* out_b   = (const float*)d_in[25];
    const float* fc1_w   = (const float*)d_in[26];
    const float* fc1_b   = (const float*)d_in[27];
    const float* fc2_w   = (const float*)d_in[28];
    const float* fc2_b   = (const float*)d_in[29];
    float* out           = (float*)d_out;

    // ---- workspace carve (all ushort-elem counts are multiples of 8) ----
    ushort_t* wsu = (ushort_t*)d_ws;
    size_t off = 0;
    auto alloc = [&](size_t n) { ushort_t* p = wsu + off; off += n; return p; };
    ushort_t* t_bf   = alloc(12582912);   // text bf16
    ushort_t* a_bf   = alloc(8388608);    // audio
    ushort_t* v_bf   = alloc(4194304);    // visual
    ushort_t* Wt_bf  = alloc(393216);
    ushort_t* Wa_bf  = alloc(262144);
    ushort_t* Wv_bf  = alloc(131072);
    ushort_t* inw_bf = alloc(2097152);    // [2][2048][512]
    ushort_t* xpf_bf = alloc(131072);     // [2][64][1024]
    ushort_t* dwf_bf = alloc(65536);      // [2][1024][32]
    ushort_t* xpb_bf = alloc(131072);
    ushort_t* dwb_bf = alloc(65536);
    ushort_t* ow_bf  = alloc(1048576);    // [2][512][1024]
    ushort_t* f1_bf  = alloc(131072);     // [256][512]
    ushort_t* b_h    = alloc(8388608);    // [M][512]
    ushort_t* b_xcf  = alloc(16777216);   // [M][1024]
    ushort_t* b_xcb  = alloc(16777216);
    ushort_t* b_szy  = alloc(16777216);   // silu(z) then y in-place
    ushort_t* b_dblf = alloc(1048576);    // [M][64]
    ushort_t* b_dblb = alloc(1048576);
    ushort_t* b_hid  = alloc(4194304);    // [M][256]
    float* b_bcf = (float*)(wsu + off); off += 2 * MTOT;
    float* b_bcb = (float*)(wsu + off); off += 2 * MTOT;
    (void)ws_size;

    // ---- weight/input conversion (one launch) ----
    CvtArgs ca;
    const float* srcs[13] = { text, audio, visual, W_text, W_audio, W_vis,
                              in_w, xproj_w, dt_w, xprojB, dt_wB, out_w, fc1_w };
    ushort_t* dsts[13] = { t_bf, a_bf, v_bf, Wt_bf, Wa_bf, Wv_bf,
                           inw_bf, xpf_bf, dwf_bf, xpb_bf, dwb_bf, ow_bf, f1_bf };
    const int ns[13] = { 12582912, 8388608, 4194304, 393216, 262144, 131072,
                         2097152, 131072, 65536, 131072, 65536, 1048576, 131072 };
    for (int i = 0; i < 13; ++i) { ca.src[i] = srcs[i]; ca.dst[i] = dsts[i]; ca.n[i] = ns[i]; }
    cvt_k<<<dim3(192, 13), 256, 0, stream>>>(ca);

    const dim3 blk(256);
    // ---- modality projections (relu) -> reps in xcf/xcb/szy (ldc=512) ----
    mgemm_k<4,4,2,2,1><<<dim3(4, 128), blk, 0, stream>>>(
        t_bf, 768, Wt_bf, 768, b_text, b_xcf, 512, 768,
        nullptr, nullptr, nullptr, nullptr, nullptr, nullptr);
    mgemm_k<4,4,2,2,1><<<dim3(4, 128), blk, 0, stream>>>(
        a_bf, 512, Wa_bf, 512, b_audio, b_xcb, 512, 512,
        nullptr, nullptr, nullptr, nullptr, nullptr, nullptr);
    mgemm_k<4,4,2,2,1><<<dim3(4, 128), blk, 0, stream>>>(
        v_bf, 256, Wv_bf, 256, b_vis, b_szy, 512, 256,
        nullptr, nullptr, nullptr, nullptr, nullptr, nullptr);
    fuseh_k<<<MTOT, 64, 0, stream>>>(b_xcf, b_xcb, b_szy, b_h);

    for (int l = 0; l < 2; ++l) {
        // in_w: [M,512] @ [2048,512]^T, split epilogue -> xcf, xcb, szy (bf16)
        mgemm_k<4,4,2,2,2><<<dim3(16, 128), blk, 0, stream>>>(
            b_h, 512, inw_bf + (size_t)l * 1048576, 512, in_b + l * 2048,
            b_xcf, 1024, 512,
            conv_w + l * 4096, conv_b + l * 1024,
            conv_wB + l * 4096, conv_bB + l * 1024, b_xcb, b_szy);
        // dbl: [M,1024] @ [64,1024]^T
        mgemm_k<2,4,4,1,0><<<dim3(1, 128), blk, 0, stream>>>(
            b_xcf, 1024, xpf_bf + (size_t)l * 65536, 1024, nullptr,
            b_dblf, 64, 1024,
            nullptr, nullptr, nullptr, nullptr, nullptr, nullptr);
        mgemm_k<2,4,4,1,0><<<dim3(1, 128), blk, 0, stream>>>(
            b_xcb, 1024, xpb_bf + (size_t)l * 65536, 1024, nullptr,
            b_dblb, 64, 1024,
            nullptr, nullptr, nullptr, nullptr, nullptr, nullptr);
        bc_k<<<MTOT / 16, blk, 0, stream>>>(b_dblf, b_dblb, b_bcf, b_bcb);
        dty_k<<<dim3(16, 128), blk, 0, stream>>>(
            b_dblf, b_dblb,
            dwf_bf + (size_t)l * 32768, dwb_bf + (size_t)l * 32768,
            dt_b + l * 1024, dt_bB + l * 1024,
            Dskip + l * 1024, DskipB + l * 1024,
            b_bcf, b_bcb, b_xcf, b_xcb, b_szy);
        // out_w: [M,1024] @ [512,1024]^T -> h
        mgemm_k<4,4,2,2,0><<<dim3(4, 128), blk, 0, stream>>>(
            b_szy, 1024, ow_bf + (size_t)l * 524288, 1024, out_b + l * 512,
            b_h, 512, 1024,
            nullptr, nullptr, nullptr, nullptr, nullptr, nullptr);
    }

    // fc1: [M,512] @ [256,512]^T, relu -> hid
    mgemm_k<4,4,2,2,1><<<dim3(2, 128), blk, 0, stream>>>(
        b_h, 512, f1_bf, 512, fc1_b, b_hid, 256, 512,
        nullptr, nullptr, nullptr, nullptr, nullptr, nullptr);
    head_k<<<MTOT / 4, blk, 0, stream>>>(b_hid, fc2_w, fc2_b, out);
}

// Round 4
// 805.207 us; speedup vs baseline: 3.2828x; 1.9368x over previous
//
#include <hip/hip_runtime.h>
#include <hip/hip_bf16.h>

#define MTOT 16384      // B*T tokens; whole net is per-token
#define DI_ 1024

typedef __attribute__((ext_vector_type(8))) short bfrag;   // 8 bf16
typedef __attribute__((ext_vector_type(4))) float ffrag;   // 4 f32 acc
typedef unsigned short ushort_t;

__device__ __forceinline__ float us2f(ushort_t u) {
    union { float f; unsigned int i; } c; c.i = ((unsigned int)u) << 16; return c.f;
}
__device__ __forceinline__ ushort_t f2us(float f) {
    __hip_bfloat16 b = __float2bfloat16(f);
    return *(ushort_t*)&b;
}
__device__ __forceinline__ float silu_f(float x) {
    return x * __builtin_amdgcn_rcpf(1.0f + __expf(-x));
}
__device__ __forceinline__ float softplus_f(float x) {
    return fmaxf(x, 0.0f) + __logf(1.0f + __expf(-fabsf(x)));
}
__device__ __forceinline__ void glds16(const ushort_t* g, ushort_t* l) {
    __builtin_amdgcn_global_load_lds(
        (const __attribute__((address_space(1))) void*)g,
        (__attribute__((address_space(3))) void*)l, 16, 0, 0);
}
__device__ __forceinline__ uint4 pack8(const float* v) {
    union { uint4 u; ushort_t s[8]; } r;
#pragma unroll
    for (int e = 0; e < 8; ++e) r.s[e] = f2us(v[e]);
    return r.u;
}

// ---------------------------------------------------------------------------
// f32 -> bf16 conversion for 13 arrays in one launch
// ---------------------------------------------------------------------------
struct CvtArgs { const float* src[13]; ushort_t* dst[13]; int n[13]; };
__global__ __launch_bounds__(256) void cvt_k(CvtArgs a)
{
    const int id = blockIdx.y;
    const int n4 = a.n[id] >> 2;
    const float* s = a.src[id];
    ushort_t* d = a.dst[id];
    const int stride = gridDim.x * blockDim.x;
    for (int i = blockIdx.x * blockDim.x + threadIdx.x; i < n4; i += stride) {
        float4 v = *(const float4*)(s + (size_t)i * 4);
        ushort_t o[4] = { f2us(v.x), f2us(v.y), f2us(v.z), f2us(v.w) };
        *(uint2*)(d + (size_t)i * 4) = *(uint2*)o;
    }
}

// ---------------------------------------------------------------------------
// MFMA NT GEMM 128x128, BK=32, 4 waves. global_load_lds staging (width 16),
// linear LDS + XOR k-slot swizzle applied to global src AND ds_read addrs.
// Epilogue: LDS f32 transpose -> coalesced uint4 bf16 stores.
// EPI: 0 none, 1 relu, 2 in_w split (xcf/xcb silu-conv | silu(z))
// ---------------------------------------------------------------------------
template <int EPI>
__global__ __launch_bounds__(256) void mgemm_k(
    const ushort_t* __restrict__ A, int lda,
    const ushort_t* __restrict__ W, int ldw,
    const float* __restrict__ bias,
    ushort_t* __restrict__ C, int ldc, int K,
    const float* __restrict__ cwf, const float* __restrict__ cbf,
    const float* __restrict__ cwb, const float* __restrict__ cbb,
    ushort_t* __restrict__ out2, ushort_t* __restrict__ out3)
{
    constexpr int BM = 128, BN = 128, TP = 132;
    __shared__ char smem[16896];   // max(staging 16384, transpose 32*132*4)
    ushort_t* SMu = (ushort_t*)smem;

    const int tid = threadIdx.x;
    const int lane = tid & 63;
    const int w = tid >> 6;
    const int wr = w >> 1, wc = w & 1;
    const int m0 = blockIdx.y * BM, n0 = blockIdx.x * BN;

    // staging: 16 wave-loads of 1KB (lw = w*4+q); loads 0..7 = A, 8..15 = W
    const ushort_t* gsrc[4];
    ushort_t* ldst[4];
#pragma unroll
    for (int q = 0; q < 4; ++q) {
        const int lw = w * 4 + q;
        const int c = lw * 64 + lane;
        ldst[q] = SMu + (size_t)lw * 512;
        if (c < BM * 4) {
            const int row = c >> 2, slot = c & 3;
            const int gslot = slot ^ ((row >> 1) & 3);
            gsrc[q] = A + (size_t)(m0 + row) * lda + gslot * 8;
        } else {
            const int c2 = c - BM * 4;
            const int row = c2 >> 2, slot = c2 & 3;
            const int gslot = slot ^ ((row >> 1) & 3);
            gsrc[q] = W + (size_t)(n0 + row) * ldw + gslot * 8;
        }
    }

    // fragment ds_read offsets (swizzle matches staging)
    const int kg = lane >> 4;
    int aoff[4], boff[4];
#pragma unroll
    for (int i = 0; i < 4; ++i) {
        const int r = wr * 64 + i * 16 + (lane & 15);
        aoff[i] = r * 32 + ((kg ^ ((r >> 1) & 3)) * 8);
        const int rw = wc * 64 + i * 16 + (lane & 15);
        boff[i] = BM * 32 + rw * 32 + ((kg ^ ((rw >> 1) & 3)) * 8);
    }

    ffrag acc[4][4];
#pragma unroll
    for (int i = 0; i < 4; ++i)
#pragma unroll
        for (int j = 0; j < 4; ++j) acc[i][j] = (ffrag){0.f, 0.f, 0.f, 0.f};

    const int NT = K >> 5;
    for (int t = 0; t < NT; ++t) {
        const int kk = t * 32;
#pragma unroll
        for (int q = 0; q < 4; ++q) glds16(gsrc[q] + kk, ldst[q]);
        __syncthreads();                     // drain vmcnt, all staged
        bfrag af[4], bw[4];
#pragma unroll
        for (int i = 0; i < 4; ++i) af[i] = *(const bfrag*)(SMu + aoff[i]);
#pragma unroll
        for (int j = 0; j < 4; ++j) bw[j] = *(const bfrag*)(SMu + boff[j]);
#pragma unroll
        for (int i = 0; i < 4; ++i)
#pragma unroll
            for (int j = 0; j < 4; ++j)
                acc[i][j] = __builtin_amdgcn_mfma_f32_16x16x32_bf16(
                    af[i], bw[j], acc[i][j], 0, 0, 0);
        __syncthreads();                     // reads done before next stage
    }

    float bj[4];
#pragma unroll
    for (int j = 0; j < 4; ++j) {
        const int col = n0 + wc * 64 + j * 16 + (lane & 15);
        bj[j] = bias ? bias[col] : 0.0f;
    }

    float* lt = (float*)smem;
    const bool lo = (EPI != 2) || (n0 < DI_);

    for (int i = 0; i < 4; ++i) {            // 32-row chunks
        __syncthreads();
#pragma unroll
        for (int j = 0; j < 4; ++j)
#pragma unroll
            for (int r = 0; r < 4; ++r)
                lt[(wr * 16 + (lane >> 4) * 4 + r) * TP + wc * 64 + j * 16 + (lane & 15)]
                    = acc[i][j][r] + bj[j];
        __syncthreads();
#pragma unroll
        for (int p = 0; p < 2; ++p) {
            const int lrow = p * 16 + (tid >> 4);
            const int cg = tid & 15;
            const int grow = m0 + (lrow >> 4) * 64 + i * 16 + (lrow & 15);
            const int gc = n0 + cg * 8;
            float4 v0 = *(float4*)&lt[lrow * TP + cg * 8];
            float4 v1 = *(float4*)&lt[lrow * TP + cg * 8 + 4];
            float v[8] = { v0.x, v0.y, v0.z, v0.w, v1.x, v1.y, v1.z, v1.w };
            if (EPI == 0) {
                *(uint4*)(C + (size_t)grow * ldc + gc) = pack8(v);
            } else if (EPI == 1) {
                float rv[8];
#pragma unroll
                for (int e = 0; e < 8; ++e) rv[e] = fmaxf(v[e], 0.0f);
                *(uint4*)(C + (size_t)grow * ldc + gc) = pack8(rv);
            } else {
                if (lo) {
                    float vf[8], vb[8];
#pragma unroll
                    for (int e = 0; e < 8; ++e) {
                        const int c = gc + e;
                        vf[e] = silu_f(v[e] * cwf[c * 4 + 3] + cbf[c]);
                        vb[e] = silu_f(v[e] * cwb[c * 4 + 3] + cbb[c]);
                    }
                    *(uint4*)(C + (size_t)grow * DI_ + gc)    = pack8(vf);
                    *(uint4*)(out2 + (size_t)grow * DI_ + gc) = pack8(vb);
                } else {
                    float vz[8];
#pragma unroll
                    for (int e = 0; e < 8; ++e) vz[e] = silu_f(v[e]);
                    *(uint4*)(out3 + (size_t)grow * DI_ + (gc - DI_)) = pack8(vz);
                }
            }
        }
    }
}

// ---------------------------------------------------------------------------
// dbl GEMM 64x64 (K=1024), fwd+bwd via blockIdx.y. Computes
// dbl = xc @ xproj^T; stores ONLY cols 0..31 (dt_in), and fuses
// bc[r] = sum_s dbl[r,32+s]*dbl[r,48+s] (from f32 acc) -> bco.
// ---------------------------------------------------------------------------
__global__ __launch_bounds__(256) void dbl_k(
    const ushort_t* __restrict__ Afwd, const ushort_t* __restrict__ Abwd,
    const ushort_t* __restrict__ Wfwd, const ushort_t* __restrict__ Wbwd,
    ushort_t* __restrict__ Dfwd, ushort_t* __restrict__ Dbwd,
    float* __restrict__ bcFo, float* __restrict__ bcBo)
{
    constexpr int BM = 64, TP = 36;
    __shared__ char smem[8192];   // staging 8192 > transpose 32*36*4=4608
    ushort_t* SMu = (ushort_t*)smem;

    const int tid = threadIdx.x;
    const int lane = tid & 63;
    const int w = tid >> 6;
    const int wr = w >> 1, wc = w & 1;
    const int m0 = blockIdx.x * 64;
    const ushort_t* A = blockIdx.y ? Abwd : Afwd;
    const ushort_t* W = blockIdx.y ? Wbwd : Wfwd;
    ushort_t* D = blockIdx.y ? Dbwd : Dfwd;
    float* bco = blockIdx.y ? bcBo : bcFo;

    const ushort_t* gsrc[2];
    ushort_t* ldst[2];
#pragma unroll
    for (int q = 0; q < 2; ++q) {
        const int lw = w * 2 + q;
        const int c = lw * 64 + lane;
        ldst[q] = SMu + (size_t)lw * 512;
        if (c < BM * 4) {
            const int row = c >> 2, slot = c & 3;
            const int gslot = slot ^ ((row >> 1) & 3);
            gsrc[q] = A + (size_t)(m0 + row) * 1024 + gslot * 8;
        } else {
            const int c2 = c - BM * 4;
            const int row = c2 >> 2, slot = c2 & 3;
            const int gslot = slot ^ ((row >> 1) & 3);
            gsrc[q] = W + (size_t)row * 1024 + gslot * 8;
        }
    }

    const int kg = lane >> 4;
    int aoff[2], boff[2];
#pragma unroll
    for (int i = 0; i < 2; ++i) {
        const int r = wr * 32 + i * 16 + (lane & 15);
        aoff[i] = r * 32 + ((kg ^ ((r >> 1) & 3)) * 8);
        const int rw = wc * 32 + i * 16 + (lane & 15);
        boff[i] = BM * 32 + rw * 32 + ((kg ^ ((rw >> 1) & 3)) * 8);
    }

    ffrag acc[2][2];
#pragma unroll
    for (int i = 0; i < 2; ++i)
#pragma unroll
        for (int j = 0; j < 2; ++j) acc[i][j] = (ffrag){0.f, 0.f, 0.f, 0.f};

    for (int t = 0; t < 32; ++t) {
        const int kk = t * 32;
#pragma unroll
        for (int q = 0; q < 2; ++q) glds16(gsrc[q] + kk, ldst[q]);
        __syncthreads();
        bfrag af[2], bw[2];
#pragma unroll
        for (int i = 0; i < 2; ++i) af[i] = *(const bfrag*)(SMu + aoff[i]);
#pragma unroll
        for (int j = 0; j < 2; ++j) bw[j] = *(const bfrag*)(SMu + boff[j]);
#pragma unroll
        for (int i = 0; i < 2; ++i)
#pragma unroll
            for (int j = 0; j < 2; ++j)
                acc[i][j] = __builtin_amdgcn_mfma_f32_16x16x32_bf16(
                    af[i], bw[j], acc[i][j], 0, 0, 0);
        __syncthreads();
    }

    // bc from f32 acc: wc==1 waves own cols 32..47 (j=0) and 48..63 (j=1)
    if (wc == 1) {
#pragma unroll
        for (int i = 0; i < 2; ++i)
#pragma unroll
            for (int r = 0; r < 4; ++r) {
                float p = acc[i][0][r] * acc[i][1][r];
                p += __shfl_xor(p, 1, 64);
                p += __shfl_xor(p, 2, 64);
                p += __shfl_xor(p, 4, 64);
                p += __shfl_xor(p, 8, 64);
                if ((lane & 15) == 0)
                    bco[m0 + wr * 32 + i * 16 + (lane >> 4) * 4 + r] = p;
            }
    }

    // transpose-store cols 0..31 (wc==0 waves hold them)
    float* lt = (float*)smem;
    for (int i = 0; i < 2; ++i) {
        __syncthreads();
        if (wc == 0) {
#pragma unroll
            for (int j = 0; j < 2; ++j)
#pragma unroll
                for (int r = 0; r < 4; ++r)
                    lt[(wr * 16 + (lane >> 4) * 4 + r) * TP + j * 16 + (lane & 15)]
                        = acc[i][j][r];
        }
        __syncthreads();
        const int lrow = tid >> 3;      // 0..31
        const int cg = tid & 7;
        if (cg < 4) {
            const int grow = m0 + (lrow >> 4) * 32 + i * 16 + (lrow & 15);
            float4 v0 = *(float4*)&lt[lrow * TP + cg * 8];
            float4 v1 = *(float4*)&lt[lrow * TP + cg * 8 + 4];
            float v[8] = { v0.x, v0.y, v0.z, v0.w, v1.x, v1.y, v1.z, v1.w };
            *(uint4*)(D + (size_t)grow * 32 + cg * 8) = pack8(v);
        }
    }
}

// ---------------------------------------------------------------------------
// dt GEMM (K=32, fwd+bwd, no LDS staging) + SSM epilogue with LDS transpose
// so all xcf/xcb/szy traffic is coalesced uint4.
//   y = (xcf*(sp(dtf)*bcf + Dpf) + xcb*(sp(dtb)*bcb + Dpb)) * sz   (in-place)
// Block: 128 rows x 64 cols, grid (16, 128).
// ---------------------------------------------------------------------------
__global__ __launch_bounds__(256) void dty_k(
    const ushort_t* __restrict__ dblf, const ushort_t* __restrict__ dblb,
    const ushort_t* __restrict__ wtf,  const ushort_t* __restrict__ wtb,
    const float* __restrict__ dbf, const float* __restrict__ dbb,
    const float* __restrict__ Dpf, const float* __restrict__ Dpb,
    const float* __restrict__ bcf, const float* __restrict__ bcb,
    const ushort_t* __restrict__ xcf, const ushort_t* __restrict__ xcb,
    ushort_t* szy)
{
    __shared__ float ltF[64 * 68];
    __shared__ float ltB[64 * 68];
    const int tid = threadIdx.x, lane = tid & 63, w = tid >> 6;
    const int m0 = blockIdx.y * 128, n0 = blockIdx.x * 64;
    const int koff = (lane >> 4) * 8;

    bfrag aF[2], aB[2], wF[4], wB[4];
#pragma unroll
    for (int i = 0; i < 2; ++i) {
        const int row = m0 + w * 32 + i * 16 + (lane & 15);
        aF[i] = *(const bfrag*)(dblf + (size_t)row * 32 + koff);
        aB[i] = *(const bfrag*)(dblb + (size_t)row * 32 + koff);
    }
#pragma unroll
    for (int j = 0; j < 4; ++j) {
        const int col = n0 + j * 16 + (lane & 15);
        wF[j] = *(const bfrag*)(wtf + (size_t)col * 32 + koff);
        wB[j] = *(const bfrag*)(wtb + (size_t)col * 32 + koff);
    }
    ffrag accF[2][4], accB[2][4];
#pragma unroll
    for (int i = 0; i < 2; ++i)
#pragma unroll
        for (int j = 0; j < 4; ++j) {
            ffrag z = (ffrag){0.f, 0.f, 0.f, 0.f};
            accF[i][j] = __builtin_amdgcn_mfma_f32_16x16x32_bf16(aF[i], wF[j], z, 0, 0, 0);
            z = (ffrag){0.f, 0.f, 0.f, 0.f};
            accB[i][j] = __builtin_amdgcn_mfma_f32_16x16x32_bf16(aB[i], wB[j], z, 0, 0, 0);
        }

    float dbfj[4], dbbj[4];
#pragma unroll
    for (int j = 0; j < 4; ++j) {
        const int c = n0 + j * 16 + (lane & 15);
        dbfj[j] = dbf[c]; dbbj[j] = dbb[c];
    }

    for (int i = 0; i < 2; ++i) {
        __syncthreads();
#pragma unroll
        for (int j = 0; j < 4; ++j)
#pragma unroll
            for (int r = 0; r < 4; ++r) {
                const int lr = w * 16 + (lane >> 4) * 4 + r;
                const int cc = j * 16 + (lane & 15);
                ltF[lr * 68 + cc] = accF[i][j][r] + dbfj[j];
                ltB[lr * 68 + cc] = accB[i][j][r] + dbbj[j];
            }
        __syncthreads();
        const int lrow = tid >> 2;      // 0..63
        const int cg = tid & 3;         // x16 cols
        const int grow = m0 + (lrow >> 4) * 32 + i * 16 + (lrow & 15);
        const float vbcf = bcf[grow], vbcb = bcb[grow];
#pragma unroll
        for (int h = 0; h < 2; ++h) {
            const int c0 = cg * 16 + h * 8;
            const int gc = n0 + c0;
            const size_t base = (size_t)grow * DI_ + gc;
            uint4 xf4 = *(const uint4*)(xcf + base);
            uint4 xb4 = *(const uint4*)(xcb + base);
            uint4 sz4 = *(const uint4*)(szy + base);
            const ushort_t* xf = (const ushort_t*)&xf4;
            const ushort_t* xb = (const ushort_t*)&xb4;
            const ushort_t* sz = (const ushort_t*)&sz4;
            float v[8];
#pragma unroll
            for (int e = 0; e < 8; ++e) {
                const float dtf = softplus_f(ltF[lrow * 68 + c0 + e]);
                const float dtb = softplus_f(ltB[lrow * 68 + c0 + e]);
                const float vf = us2f(xf[e]) * (dtf * vbcf + Dpf[gc + e]);
                const float vb = us2f(xb[e]) * (dtb * vbcb + Dpb[gc + e]);
                v[e] = (vf + vb) * us2f(sz[e]);
            }
            *(uint4*)(szy + base) = pack8(v);
        }
    }
}

// ---------------------------------------------------------------------------
// Modality fusion: one wave/token.
// ---------------------------------------------------------------------------
__global__ __launch_bounds__(64) void fuseh_k(
    const ushort_t* __restrict__ r0, const ushort_t* __restrict__ r1,
    const ushort_t* __restrict__ r2, ushort_t* __restrict__ h)
{
    const int t = blockIdx.x;
    const int lane = threadIdx.x;
    uint4 raw0 = *(const uint4*)(r0 + (size_t)t * 512 + lane * 8);
    uint4 raw1 = *(const uint4*)(r1 + (size_t)t * 512 + lane * 8);
    uint4 raw2 = *(const uint4*)(r2 + (size_t)t * 512 + lane * 8);
    const ushort_t* p0 = (const ushort_t*)&raw0;
    const ushort_t* p1 = (const ushort_t*)&raw1;
    const ushort_t* p2 = (const ushort_t*)&raw2;
    float v0[8], v1[8], v2[8];
    float s0 = 0.f, s1 = 0.f, s2 = 0.f;
#pragma unroll
    for (int j = 0; j < 8; ++j) {
        v0[j] = us2f(p0[j]); v1[j] = us2f(p1[j]); v2[j] = us2f(p2[j]);
        s0 += v0[j] * v0[j]; s1 += v1[j] * v1[j]; s2 += v2[j] * v2[j];
    }
#pragma unroll
    for (int m = 32; m >= 1; m >>= 1) {
        s0 += __shfl_xor(s0, m, 64);
        s1 += __shfl_xor(s1, m, 64);
        s2 += __shfl_xor(s2, m, 64);
    }
    const float n0 = sqrtf(s0), n1 = sqrtf(s1), n2 = sqrtf(s2);
    const float mx = fmaxf(n0, fmaxf(n1, n2));
    const float e0 = __expf(n0 - mx), e1 = __expf(n1 - mx), e2 = __expf(n2 - mx);
    const float inv = __builtin_amdgcn_rcpf(e0 + e1 + e2);
    const float w0 = e0 * inv / fmaxf(n0, 1e-12f);
    const float w1 = e1 * inv / fmaxf(n1, 1e-12f);
    const float w2 = e2 * inv / fmaxf(n2, 1e-12f);
    float o[8];
#pragma unroll
    for (int j = 0; j < 8; ++j) o[j] = w0 * v0[j] + w1 * v1[j] + w2 * v2[j];
    *(uint4*)(h + (size_t)t * 512 + lane * 8) = pack8(o);
}

// ---------------------------------------------------------------------------
// Head: logits = tanh(hid @ fc2^T + b), log_softmax(2). OUTPUT FLOAT32.
// ---------------------------------------------------------------------------
__global__ __launch_bounds__(256) void head_k(
    const ushort_t* __restrict__ hid, const float* __restrict__ fc2w,
    const float* __restrict__ fc2b, float* __restrict__ out)
{
    const int tid = threadIdx.x;
    const int lane = tid & 63;
    const int t = blockIdx.x * 4 + (tid >> 6);
    uint2 raw = *(const uint2*)(hid + (size_t)t * 256 + lane * 4);
    const ushort_t* hp = (const ushort_t*)&raw;
    float4 w0 = *(const float4*)(fc2w + lane * 4);
    float4 w1 = *(const float4*)(fc2w + 256 + lane * 4);
    float h0 = us2f(hp[0]), h1 = us2f(hp[1]), h2 = us2f(hp[2]), h3 = us2f(hp[3]);
    float d0 = h0 * w0.x + h1 * w0.y + h2 * w0.z + h3 * w0.w;
    float d1 = h0 * w1.x + h1 * w1.y + h2 * w1.z + h3 * w1.w;
#pragma unroll
    for (int m = 32; m >= 1; m >>= 1) {
        d0 += __shfl_xor(d0, m, 64);
        d1 += __shfl_xor(d1, m, 64);
    }
    if (lane == 0) {
        const float l0 = tanhf(d0 + fc2b[0]);
        const float l1 = tanhf(d1 + fc2b[1]);
        const float mx = fmaxf(l0, l1);
        const float lse = mx + __logf(__expf(l0 - mx) + __expf(l1 - mx));
        out[(size_t)t * 2 + 0] = l0 - lse;
        out[(size_t)t * 2 + 1] = l1 - lse;
    }
}

// ---------------------------------------------------------------------------
extern "C" void kernel_launch(void* const* d_in, const int* in_sizes, int n_in,
                              void* d_out, int out_size, void* d_ws, size_t ws_size,
                              hipStream_t stream)
{
    const float* text    = (const float*)d_in[0];
    const float* audio   = (const float*)d_in[1];
    const float* visual  = (const float*)d_in[3];
    const float* W_text  = (const float*)d_in[4];
    const float* b_text  = (const float*)d_in[5];
    const float* W_audio = (const float*)d_in[6];
    const float* b_audio = (const float*)d_in[7];
    const float* W_vis   = (const float*)d_in[8];
    const float* b_vis   = (const float*)d_in[9];
    const float* in_w    = (const float*)d_in[10];
    const float* in_b    = (const float*)d_in[11];
    const float* conv_w  = (const float*)d_in[12];
    const float* conv_b  = (const float*)d_in[13];
    const float* xproj_w = (const float*)d_in[14];
    const float* dt_w    = (const float*)d_in[15];
    const float* dt_b    = (const float*)d_in[16];
    const float* Dskip   = (const float*)d_in[17];
    const float* conv_wB = (const float*)d_in[18];
    const float* conv_bB = (const float*)d_in[19];
    const float* xprojB  = (const float*)d_in[20];
    const float* dt_wB   = (const float*)d_in[21];
    const float* dt_bB   = (const float*)d_in[22];
    const float* DskipB  = (const float*)d_in[23];
    const float* out_w   = (const float*)d_in[24];
    const float* out_b   = (const float*)d_in[25];
    const float* fc1_w   = (const float*)d_in[26];
    const float* fc1_b   = (const float*)d_in[27];
    const float* fc2_w   = (const float*)d_in[28];
    const float* fc2_b   = (const float*)d_in[29];
    float* out           = (float*)d_out;

    // ---- workspace carve ----
    ushort_t* wsu = (ushort_t*)d_ws;
    size_t off = 0;
    auto alloc = [&](size_t n) { ushort_t* p = wsu + off; off += n; return p; };
    ushort_t* t_bf   = alloc(12582912);
    ushort_t* a_bf   = alloc(8388608);
    ushort_t* v_bf   = alloc(4194304);
    ushort_t* Wt_bf  = alloc(393216);
    ushort_t* Wa_bf  = alloc(262144);
    ushort_t* Wv_bf  = alloc(131072);
    ushort_t* inw_bf = alloc(2097152);    // [2][2048][512]
    ushort_t* xpf_bf = alloc(131072);     // [2][64][1024]
    ushort_t* dwf_bf = alloc(65536);      // [2][1024][32]
    ushort_t* xpb_bf = alloc(131072);
    ushort_t* dwb_bf = alloc(65536);
    ushort_t* ow_bf  = alloc(1048576);    // [2][512][1024]
    ushort_t* f1_bf  = alloc(131072);     // [256][512]
    ushort_t* b_h    = alloc(8388608);    // [M][512]
    ushort_t* b_xcf  = alloc(16777216);   // [M][1024]
    ushort_t* b_xcb  = alloc(16777216);
    ushort_t* b_szy  = alloc(16777216);   // silu(z), then y in-place
    ushort_t* b_dblf = alloc(524288);     // [M][32]
    ushort_t* b_dblb = alloc(524288);
    ushort_t* b_hid  = alloc(4194304);    // [M][256]
    float* b_bcf = (float*)(wsu + off); off += 2 * MTOT;
    float* b_bcb = (float*)(wsu + off); off += 2 * MTOT;
    (void)ws_size;

    // ---- conversions ----
    CvtArgs ca;
    const float* srcs[13] = { text, audio, visual, W_text, W_audio, W_vis,
                              in_w, xproj_w, dt_w, xprojB, dt_wB, out_w, fc1_w };
    ushort_t* dsts[13] = { t_bf, a_bf, v_bf, Wt_bf, Wa_bf, Wv_bf,
                           inw_bf, xpf_bf, dwf_bf, xpb_bf, dwb_bf, ow_bf, f1_bf };
    const int ns[13] = { 12582912, 8388608, 4194304, 393216, 262144, 131072,
                         2097152, 131072, 65536, 131072, 65536, 1048576, 131072 };
    for (int i = 0; i < 13; ++i) { ca.src[i] = srcs[i]; ca.dst[i] = dsts[i]; ca.n[i] = ns[i]; }
    cvt_k<<<dim3(192, 13), 256, 0, stream>>>(ca);

    const dim3 blk(256);
    // modality projections (relu) -> reps staged in xcf/xcb/szy (ldc=512)
    mgemm_k<1><<<dim3(4, 128), blk, 0, stream>>>(
        t_bf, 768, Wt_bf, 768, b_text, b_xcf, 512, 768,
        nullptr, nullptr, nullptr, nullptr, nullptr, nullptr);
    mgemm_k<1><<<dim3(4, 128), blk, 0, stream>>>(
        a_bf, 512, Wa_bf, 512, b_audio, b_xcb, 512, 512,
        nullptr, nullptr, nullptr, nullptr, nullptr, nullptr);
    mgemm_k<1><<<dim3(4, 128), blk, 0, stream>>>(
        v_bf, 256, Wv_bf, 256, b_vis, b_szy, 512, 256,
        nullptr, nullptr, nullptr, nullptr, nullptr, nullptr);
    fuseh_k<<<MTOT, 64, 0, stream>>>(b_xcf, b_xcb, b_szy, b_h);

    for (int l = 0; l < 2; ++l) {
        mgemm_k<2><<<dim3(16, 128), blk, 0, stream>>>(
            b_h, 512, inw_bf + (size_t)l * 1048576, 512, in_b + l * 2048,
            b_xcf, 1024, 512,
            conv_w + l * 4096, conv_b + l * 1024,
            conv_wB + l * 4096, conv_bB + l * 1024, b_xcb, b_szy);
        dbl_k<<<dim3(256, 2), blk, 0, stream>>>(
            b_xcf, b_xcb,
            xpf_bf + (size_t)l * 65536, xpb_bf + (size_t)l * 65536,
            b_dblf, b_dblb, b_bcf, b_bcb);
        dty_k<<<dim3(16, 128), blk, 0, stream>>>(
            b_dblf, b_dblb,
            dwf_bf + (size_t)l * 32768, dwb_bf + (size_t)l * 32768,
            dt_b + l * 1024, dt_bB + l * 1024,
            Dskip + l * 1024, DskipB + l * 1024,
            b_bcf, b_bcb, b_xcf, b_xcb, b_szy);
        mgemm_k<0><<<dim3(4, 128), blk, 0, stream>>>(
            b_szy, 1024, ow_bf + (size_t)l * 524288, 1024, out_b + l * 512,
            b_h, 512, 1024,
            nullptr, nullptr, nullptr, nullptr, nullptr, nullptr);
    }

    mgemm_k<1><<<dim3(2, 128), blk, 0, stream>>>(
        b_h, 512, f1_bf, 512, fc1_b, b_hid, 256, 512,
        nullptr, nullptr, nullptr, nullptr, nullptr, nullptr);
    head_k<<<MTOT / 4, blk, 0, stream>>>(b_hid, fc2_w, fc2_b, out);
}

// Round 6
// 758.203 us; speedup vs baseline: 3.4863x; 1.0620x over previous
//
#include <hip/hip_runtime.h>
#include <hip/hip_bf16.h>

#define MTOT 16384      // B*T tokens; whole net is per-token
#define DI_ 1024

typedef __attribute__((ext_vector_type(8))) short bfrag;   // 8 bf16
typedef __attribute__((ext_vector_type(4))) float ffrag;   // 4 f32 acc
typedef unsigned short ushort_t;

__device__ __forceinline__ float us2f(ushort_t u) {
    union { float f; unsigned int i; } c; c.i = ((unsigned int)u) << 16; return c.f;
}
__device__ __forceinline__ ushort_t f2us(float f) {
    __hip_bfloat16 b = __float2bfloat16(f);
    return *(ushort_t*)&b;
}
__device__ __forceinline__ float silu_f(float x) {
    return x * __builtin_amdgcn_rcpf(1.0f + __expf(-x));
}
__device__ __forceinline__ float softplus_f(float x) {
    return fmaxf(x, 0.0f) + __logf(1.0f + __expf(-fabsf(x)));
}
__device__ __forceinline__ void glds16(const ushort_t* g, ushort_t* l) {
    __builtin_amdgcn_global_load_lds(
        (const __attribute__((address_space(1))) void*)g,
        (__attribute__((address_space(3))) void*)l, 16, 0, 0);
}
__device__ __forceinline__ void wait_vm0_barrier() {
    asm volatile("s_waitcnt vmcnt(0)" ::: "memory");
    __builtin_amdgcn_s_barrier();
    __builtin_amdgcn_sched_barrier(0);
}
__device__ __forceinline__ uint4 pack8(const float* v) {
    union { uint4 u; ushort_t s[8]; } r;
#pragma unroll
    for (int e = 0; e < 8; ++e) r.s[e] = f2us(v[e]);
    return r.u;
}

// ---------------------------------------------------------------------------
// f32 -> bf16 conversion for 13 arrays in one launch
// ---------------------------------------------------------------------------
struct CvtArgs { const float* src[13]; ushort_t* dst[13]; int n[13]; };
__global__ __launch_bounds__(256) void cvt_k(CvtArgs a)
{
    const int id = blockIdx.y;
    const int n4 = a.n[id] >> 2;
    const float* s = a.src[id];
    ushort_t* d = a.dst[id];
    const int stride = gridDim.x * blockDim.x;
    for (int i = blockIdx.x * blockDim.x + threadIdx.x; i < n4; i += stride) {
        float4 v = *(const float4*)(s + (size_t)i * 4);
        ushort_t o[4] = { f2us(v.x), f2us(v.y), f2us(v.z), f2us(v.w) };
        *(uint2*)(d + (size_t)i * 4) = *(uint2*)o;
    }
}

// ---------------------------------------------------------------------------
// MFMA NT GEMM 128x128, BK=32, 4 waves. Double-buffered global_load_lds
// pipeline: STAGE(t+1) issued before compute(t); one vmcnt(0)+s_barrier per
// K-step (T3 minimal 2-phase; no compiler full-drain mid-loop).
// Epilogue: LDS f32 transpose -> coalesced uint4 bf16 stores.
// EPI: 0 none, 1 relu, 2 in_w split (xcf/xcb silu-conv | silu(z))
// ---------------------------------------------------------------------------
template <int EPI>
__global__ __launch_bounds__(256) void mgemm_k(
    const ushort_t* __restrict__ A, int lda,
    const ushort_t* __restrict__ W, int ldw,
    const float* __restrict__ bias,
    ushort_t* __restrict__ C, int ldc, int K,
    const float* __restrict__ cwf, const float* __restrict__ cbf,
    const float* __restrict__ cwb, const float* __restrict__ cbb,
    ushort_t* __restrict__ out2, ushort_t* __restrict__ out3)
{
    constexpr int BM = 128, BN = 128, TP = 132;
    constexpr int BUF = 8192;              // ushorts per staging buffer (16 KB)
    __shared__ char smem[32768];           // 2 buffers; epilogue reuses (16896B)
    ushort_t* SMu = (ushort_t*)smem;

    const int tid = threadIdx.x;
    const int lane = tid & 63;
    const int w = tid >> 6;
    const int wr = w >> 1, wc = w & 1;
    const int m0 = blockIdx.y * BM, n0 = blockIdx.x * BN;

    // staging: 16 wave-loads of 1KB (lw = w*4+q); loads 0..7 = A, 8..15 = W
    const ushort_t* gsrc[4];
    ushort_t* ldst[4];
#pragma unroll
    for (int q = 0; q < 4; ++q) {
        const int lw = w * 4 + q;
        const int c = lw * 64 + lane;
        ldst[q] = SMu + (size_t)lw * 512;
        if (c < BM * 4) {
            const int row = c >> 2, slot = c & 3;
            const int gslot = slot ^ ((row >> 1) & 3);
            gsrc[q] = A + (size_t)(m0 + row) * lda + gslot * 8;
        } else {
            const int c2 = c - BM * 4;
            const int row = c2 >> 2, slot = c2 & 3;
            const int gslot = slot ^ ((row >> 1) & 3);
            gsrc[q] = W + (size_t)(n0 + row) * ldw + gslot * 8;
        }
    }

    // fragment ds_read offsets (swizzle matches staging)
    const int kg = lane >> 4;
    int aoff[4], boff[4];
#pragma unroll
    for (int i = 0; i < 4; ++i) {
        const int r = wr * 64 + i * 16 + (lane & 15);
        aoff[i] = r * 32 + ((kg ^ ((r >> 1) & 3)) * 8);
        const int rw = wc * 64 + i * 16 + (lane & 15);
        boff[i] = BM * 32 + rw * 32 + ((kg ^ ((rw >> 1) & 3)) * 8);
    }

    ffrag acc[4][4];
#pragma unroll
    for (int i = 0; i < 4; ++i)
#pragma unroll
        for (int j = 0; j < 4; ++j) acc[i][j] = (ffrag){0.f, 0.f, 0.f, 0.f};

    const int NT = K >> 5;
    // prologue: stage tile 0 into buffer 0
#pragma unroll
    for (int q = 0; q < 4; ++q) glds16(gsrc[q], ldst[q]);
    wait_vm0_barrier();

    int cur = 0;
    for (int t = 0; t < NT; ++t) {
        if (t + 1 < NT) {
            const int nb = (cur ^ 1) * BUF;
#pragma unroll
            for (int q = 0; q < 4; ++q)
                glds16(gsrc[q] + (t + 1) * 32, ldst[q] + nb);
        }
        const ushort_t* Sb = SMu + cur * BUF;
        bfrag af[4], bw[4];
#pragma unroll
        for (int i = 0; i < 4; ++i) af[i] = *(const bfrag*)(Sb + aoff[i]);
#pragma unroll
        for (int j = 0; j < 4; ++j) bw[j] = *(const bfrag*)(Sb + boff[j]);
#pragma unroll
        for (int i = 0; i < 4; ++i)
#pragma unroll
            for (int j = 0; j < 4; ++j)
                acc[i][j] = __builtin_amdgcn_mfma_f32_16x16x32_bf16(
                    af[i], bw[j], acc[i][j], 0, 0, 0);
        if (t + 1 < NT) {
            wait_vm0_barrier();   // next tile staged; prev reads done by reg-dep
            cur ^= 1;
        }
    }

    float bj[4];
#pragma unroll
    for (int j = 0; j < 4; ++j) {
        const int col = n0 + wc * 64 + j * 16 + (lane & 15);
        bj[j] = bias ? bias[col] : 0.0f;
    }

    float* lt = (float*)smem;
    const bool lo = (EPI != 2) || (n0 < DI_);

    for (int i = 0; i < 4; ++i) {            // 32-row chunks
        __syncthreads();
#pragma unroll
        for (int j = 0; j < 4; ++j)
#pragma unroll
            for (int r = 0; r < 4; ++r)
                lt[(wr * 16 + (lane >> 4) * 4 + r) * TP + wc * 64 + j * 16 + (lane & 15)]
                    = acc[i][j][r] + bj[j];
        __syncthreads();
#pragma unroll
        for (int p = 0; p < 2; ++p) {
            const int lrow = p * 16 + (tid >> 4);
            const int cg = tid & 15;
            const int grow = m0 + (lrow >> 4) * 64 + i * 16 + (lrow & 15);
            const int gc = n0 + cg * 8;
            float4 v0 = *(float4*)&lt[lrow * TP + cg * 8];
            float4 v1 = *(float4*)&lt[lrow * TP + cg * 8 + 4];
            float v[8] = { v0.x, v0.y, v0.z, v0.w, v1.x, v1.y, v1.z, v1.w };
            if (EPI == 0) {
                *(uint4*)(C + (size_t)grow * ldc + gc) = pack8(v);
            } else if (EPI == 1) {
                float rv[8];
#pragma unroll
                for (int e = 0; e < 8; ++e) rv[e] = fmaxf(v[e], 0.0f);
                *(uint4*)(C + (size_t)grow * ldc + gc) = pack8(rv);
            } else {
                if (lo) {
                    float vf[8], vb[8];
#pragma unroll
                    for (int e = 0; e < 8; ++e) {
                        const int c = gc + e;
                        vf[e] = silu_f(v[e] * cwf[c * 4 + 3] + cbf[c]);
                        vb[e] = silu_f(v[e] * cwb[c * 4 + 3] + cbb[c]);
                    }
                    *(uint4*)(C + (size_t)grow * DI_ + gc)    = pack8(vf);
                    *(uint4*)(out2 + (size_t)grow * DI_ + gc) = pack8(vb);
                } else {
                    float vz[8];
#pragma unroll
                    for (int e = 0; e < 8; ++e) vz[e] = silu_f(v[e]);
                    *(uint4*)(out3 + (size_t)grow * DI_ + (gc - DI_)) = pack8(vz);
                }
            }
        }
    }
}

// ---------------------------------------------------------------------------
// dbl GEMM 64x64 (K=1024), fwd+bwd via blockIdx.y, double-buffered pipeline.
// dbl = xc @ xproj^T; stores ONLY cols 0..31 (dt_in); fuses
// bc[r] = sum_s dbl[r,32+s]*dbl[r,48+s] (from f32 acc).
// ---------------------------------------------------------------------------
__global__ __launch_bounds__(256) void dbl_k(
    const ushort_t* __restrict__ Afwd, const ushort_t* __restrict__ Abwd,
    const ushort_t* __restrict__ Wfwd, const ushort_t* __restrict__ Wbwd,
    ushort_t* __restrict__ Dfwd, ushort_t* __restrict__ Dbwd,
    float* __restrict__ bcFo, float* __restrict__ bcBo)
{
    constexpr int BM = 64, TP = 36;
    constexpr int BUF = 4096;             // ushorts per buffer (8 KB)
    __shared__ char smem[16384];          // 2 buffers; epilogue lt = 4608B
    ushort_t* SMu = (ushort_t*)smem;

    const int tid = threadIdx.x;
    const int lane = tid & 63;
    const int w = tid >> 6;
    const int wr = w >> 1, wc = w & 1;
    const int m0 = blockIdx.x * 64;
    const ushort_t* A = blockIdx.y ? Abwd : Afwd;
    const ushort_t* W = blockIdx.y ? Wbwd : Wfwd;
    ushort_t* D = blockIdx.y ? Dbwd : Dfwd;
    float* bco = blockIdx.y ? bcBo : bcFo;

    const ushort_t* gsrc[2];
    ushort_t* ldst[2];
#pragma unroll
    for (int q = 0; q < 2; ++q) {
        const int lw = w * 2 + q;
        const int c = lw * 64 + lane;
        ldst[q] = SMu + (size_t)lw * 512;
        if (c < BM * 4) {
            const int row = c >> 2, slot = c & 3;
            const int gslot = slot ^ ((row >> 1) & 3);
            gsrc[q] = A + (size_t)(m0 + row) * 1024 + gslot * 8;
        } else {
            const int c2 = c - BM * 4;
            const int row = c2 >> 2, slot = c2 & 3;
            const int gslot = slot ^ ((row >> 1) & 3);
            gsrc[q] = W + (size_t)row * 1024 + gslot * 8;
        }
    }

    const int kg = lane >> 4;
    int aoff[2], boff[2];
#pragma unroll
    for (int i = 0; i < 2; ++i) {
        const int r = wr * 32 + i * 16 + (lane & 15);
        aoff[i] = r * 32 + ((kg ^ ((r >> 1) & 3)) * 8);
        const int rw = wc * 32 + i * 16 + (lane & 15);
        boff[i] = BM * 32 + rw * 32 + ((kg ^ ((rw >> 1) & 3)) * 8);
    }

    ffrag acc[2][2];
#pragma unroll
    for (int i = 0; i < 2; ++i)
#pragma unroll
        for (int j = 0; j < 2; ++j) acc[i][j] = (ffrag){0.f, 0.f, 0.f, 0.f};

    // prologue
#pragma unroll
    for (int q = 0; q < 2; ++q) glds16(gsrc[q], ldst[q]);
    wait_vm0_barrier();

    int cur = 0;
    for (int t = 0; t < 32; ++t) {
        if (t + 1 < 32) {
            const int nb = (cur ^ 1) * BUF;
#pragma unroll
            for (int q = 0; q < 2; ++q)
                glds16(gsrc[q] + (t + 1) * 32, ldst[q] + nb);
        }
        const ushort_t* Sb = SMu + cur * BUF;
        bfrag af[2], bw[2];
#pragma unroll
        for (int i = 0; i < 2; ++i) af[i] = *(const bfrag*)(Sb + aoff[i]);
#pragma unroll
        for (int j = 0; j < 2; ++j) bw[j] = *(const bfrag*)(Sb + boff[j]);
#pragma unroll
        for (int i = 0; i < 2; ++i)
#pragma unroll
            for (int j = 0; j < 2; ++j)
                acc[i][j] = __builtin_amdgcn_mfma_f32_16x16x32_bf16(
                    af[i], bw[j], acc[i][j], 0, 0, 0);
        if (t + 1 < 32) {
            wait_vm0_barrier();
            cur ^= 1;
        }
    }

    // bc from f32 acc: wc==1 waves own cols 32..47 (j=0) and 48..63 (j=1)
    if (wc == 1) {
#pragma unroll
        for (int i = 0; i < 2; ++i)
#pragma unroll
            for (int r = 0; r < 4; ++r) {
                float p = acc[i][0][r] * acc[i][1][r];
                p += __shfl_xor(p, 1, 64);
                p += __shfl_xor(p, 2, 64);
                p += __shfl_xor(p, 4, 64);
                p += __shfl_xor(p, 8, 64);
                if ((lane & 15) == 0)
                    bco[m0 + wr * 32 + i * 16 + (lane >> 4) * 4 + r] = p;
            }
    }

    // transpose-store cols 0..31 (wc==0 waves hold them)
    float* lt = (float*)smem;
    for (int i = 0; i < 2; ++i) {
        __syncthreads();
        if (wc == 0) {
#pragma unroll
            for (int j = 0; j < 2; ++j)
#pragma unroll
                for (int r = 0; r < 4; ++r)
                    lt[(wr * 16 + (lane >> 4) * 4 + r) * TP + j * 16 + (lane & 15)]
                        = acc[i][j][r];
        }
        __syncthreads();
        const int lrow = tid >> 3;      // 0..31
        const int cg = tid & 7;
        if (cg < 4) {
            const int grow = m0 + (lrow >> 4) * 32 + i * 16 + (lrow & 15);
            float4 v0 = *(float4*)&lt[lrow * TP + cg * 8];
            float4 v1 = *(float4*)&lt[lrow * TP + cg * 8 + 4];
            float v[8] = { v0.x, v0.y, v0.z, v0.w, v1.x, v1.y, v1.z, v1.w };
            *(uint4*)(D + (size_t)grow * 32 + cg * 8) = pack8(v);
        }
    }
}

// ---------------------------------------------------------------------------
// dt GEMM (K=32, fwd+bwd, no LDS staging) + SSM epilogue with LDS transpose
// so all xcf/xcb/szy traffic is coalesced uint4.
//   y = (xcf*(sp(dtf)*bcf + Dpf) + xcb*(sp(dtb)*bcb + Dpb)) * sz   (in-place)
// Block: 128 rows x 64 cols, grid (16, 128).
// ---------------------------------------------------------------------------
__global__ __launch_bounds__(256) void dty_k(
    const ushort_t* __restrict__ dblf, const ushort_t* __restrict__ dblb,
    const ushort_t* __restrict__ wtf,  const ushort_t* __restrict__ wtb,
    const float* __restrict__ dbf, const float* __restrict__ dbb,
    const float* __restrict__ Dpf, const float* __restrict__ Dpb,
    const float* __restrict__ bcf, const float* __restrict__ bcb,
    const ushort_t* __restrict__ xcf, const ushort_t* __restrict__ xcb,
    ushort_t* szy)
{
    __shared__ float ltF[64 * 68];
    __shared__ float ltB[64 * 68];
    const int tid = threadIdx.x, lane = tid & 63, w = tid >> 6;
    const int m0 = blockIdx.y * 128, n0 = blockIdx.x * 64;
    const int koff = (lane >> 4) * 8;

    bfrag aF[2], aB[2], wF[4], wB[4];
#pragma unroll
    for (int i = 0; i < 2; ++i) {
        const int row = m0 + w * 32 + i * 16 + (lane & 15);
        aF[i] = *(const bfrag*)(dblf + (size_t)row * 32 + koff);
        aB[i] = *(const bfrag*)(dblb + (size_t)row * 32 + koff);
    }
#pragma unroll
    for (int j = 0; j < 4; ++j) {
        const int col = n0 + j * 16 + (lane & 15);
        wF[j] = *(const bfrag*)(wtf + (size_t)col * 32 + koff);
        wB[j] = *(const bfrag*)(wtb + (size_t)col * 32 + koff);
    }
    ffrag accF[2][4], accB[2][4];
#pragma unroll
    for (int i = 0; i < 2; ++i)
#pragma unroll
        for (int j = 0; j < 4; ++j) {
            ffrag z = (ffrag){0.f, 0.f, 0.f, 0.f};
            accF[i][j] = __builtin_amdgcn_mfma_f32_16x16x32_bf16(aF[i], wF[j], z, 0, 0, 0);
            z = (ffrag){0.f, 0.f, 0.f, 0.f};
            accB[i][j] = __builtin_amdgcn_mfma_f32_16x16x32_bf16(aB[i], wB[j], z, 0, 0, 0);
        }

    float dbfj[4], dbbj[4];
#pragma unroll
    for (int j = 0; j < 4; ++j) {
        const int c = n0 + j * 16 + (lane & 15);
        dbfj[j] = dbf[c]; dbbj[j] = dbb[c];
    }

    for (int i = 0; i < 2; ++i) {
        __syncthreads();
#pragma unroll
        for (int j = 0; j < 4; ++j)
#pragma unroll
            for (int r = 0; r < 4; ++r) {
                const int lr = w * 16 + (lane >> 4) * 4 + r;
                const int cc = j * 16 + (lane & 15);
                ltF[lr * 68 + cc] = accF[i][j][r] + dbfj[j];
                ltB[lr * 68 + cc] = accB[i][j][r] + dbbj[j];
            }
        __syncthreads();
        const int lrow = tid >> 2;      // 0..63
        const int cg = tid & 3;         // x16 cols
        const int grow = m0 + (lrow >> 4) * 32 + i * 16 + (lrow & 15);
        const float vbcf = bcf[grow], vbcb = bcb[grow];
#pragma unroll
        for (int h = 0; h < 2; ++h) {
            const int c0 = cg * 16 + h * 8;
            const int gc = n0 + c0;
            const size_t base = (size_t)grow * DI_ + gc;
            uint4 xf4 = *(const uint4*)(xcf + base);
            uint4 xb4 = *(const uint4*)(xcb + base);
            uint4 sz4 = *(const uint4*)(szy + base);
            const ushort_t* xf = (const ushort_t*)&xf4;
            const ushort_t* xb = (const ushort_t*)&xb4;
            const ushort_t* sz = (const ushort_t*)&sz4;
            float v[8];
#pragma unroll
            for (int e = 0; e < 8; ++e) {
                const float dtf = softplus_f(ltF[lrow * 68 + c0 + e]);
                const float dtb = softplus_f(ltB[lrow * 68 + c0 + e]);
                const float vf = us2f(xf[e]) * (dtf * vbcf + Dpf[gc + e]);
                const float vb = us2f(xb[e]) * (dtb * vbcb + Dpb[gc + e]);
                v[e] = (vf + vb) * us2f(sz[e]);
            }
            *(uint4*)(szy + base) = pack8(v);
        }
    }
}

// ---------------------------------------------------------------------------
// Modality fusion: 4 tokens/block, one wave per token.
// ---------------------------------------------------------------------------
__global__ __launch_bounds__(256) void fuseh_k(
    const ushort_t* __restrict__ r0, const ushort_t* __restrict__ r1,
    const ushort_t* __restrict__ r2, ushort_t* __restrict__ h)
{
    const int t = blockIdx.x * 4 + (threadIdx.x >> 6);
    const int lane = threadIdx.x & 63;
    uint4 raw0 = *(const uint4*)(r0 + (size_t)t * 512 + lane * 8);
    uint4 raw1 = *(const uint4*)(r1 + (size_t)t * 512 + lane * 8);
    uint4 raw2 = *(const uint4*)(r2 + (size_t)t * 512 + lane * 8);
    const ushort_t* p0 = (const ushort_t*)&raw0;
    const ushort_t* p1 = (const ushort_t*)&raw1;
    const ushort_t* p2 = (const ushort_t*)&raw2;
    float v0[8], v1[8], v2[8];
    float s0 = 0.f, s1 = 0.f, s2 = 0.f;
#pragma unroll
    for (int j = 0; j < 8; ++j) {
        v0[j] = us2f(p0[j]); v1[j] = us2f(p1[j]); v2[j] = us2f(p2[j]);
        s0 += v0[j] * v0[j]; s1 += v1[j] * v1[j]; s2 += v2[j] * v2[j];
    }
#pragma unroll
    for (int m = 32; m >= 1; m >>= 1) {
        s0 += __shfl_xor(s0, m, 64);
        s1 += __shfl_xor(s1, m, 64);
        s2 += __shfl_xor(s2, m, 64);
    }
    const float n0 = sqrtf(s0), n1 = sqrtf(s1), n2 = sqrtf(s2);
    const float mx = fmaxf(n0, fmaxf(n1, n2));
    const float e0 = __expf(n0 - mx), e1 = __expf(n1 - mx), e2 = __expf(n2 - mx);
    const float inv = __builtin_amdgcn_rcpf(e0 + e1 + e2);
    const float w0 = e0 * inv / fmaxf(n0, 1e-12f);
    const float w1 = e1 * inv / fmaxf(n1, 1e-12f);
    const float w2 = e2 * inv / fmaxf(n2, 1e-12f);
    float o[8];
#pragma unroll
    for (int j = 0; j < 8; ++j) o[j] = w0 * v0[j] + w1 * v1[j] + w2 * v2[j];
    *(uint4*)(h + (size_t)t * 512 + lane * 8) = pack8(o);
}

// ---------------------------------------------------------------------------
// Head: logits = tanh(hid @ fc2^T + b), log_softmax(2). OUTPUT FLOAT32.
// ---------------------------------------------------------------------------
__global__ __launch_bounds__(256) void head_k(
    const ushort_t* __restrict__ hid, const float* __restrict__ fc2w,
    const float* __restrict__ fc2b, float* __restrict__ out)
{
    const int tid = threadIdx.x;
    const int lane = tid & 63;
    const int t = blockIdx.x * 4 + (tid >> 6);
    uint2 raw = *(const uint2*)(hid + (size_t)t * 256 + lane * 4);
    const ushort_t* hp = (const ushort_t*)&raw;
    float4 w0 = *(const float4*)(fc2w + lane * 4);
    float4 w1 = *(const float4*)(fc2w + 256 + lane * 4);
    float h0 = us2f(hp[0]), h1 = us2f(hp[1]), h2 = us2f(hp[2]), h3 = us2f(hp[3]);
    float d0 = h0 * w0.x + h1 * w0.y + h2 * w0.z + h3 * w0.w;
    float d1 = h0 * w1.x + h1 * w1.y + h2 * w1.z + h3 * w1.w;
#pragma unroll
    for (int m = 32; m >= 1; m >>= 1) {
        d0 += __shfl_xor(d0, m, 64);
        d1 += __shfl_xor(d1, m, 64);
    }
    if (lane == 0) {
        const float l0 = tanhf(d0 + fc2b[0]);
        const float l1 = tanhf(d1 + fc2b[1]);
        const float mx = fmaxf(l0, l1);
        const float lse = mx + __logf(__expf(l0 - mx) + __expf(l1 - mx));
        out[(size_t)t * 2 + 0] = l0 - lse;
        out[(size_t)t * 2 + 1] = l1 - lse;
    }
}

// ---------------------------------------------------------------------------
extern "C" void kernel_launch(void* const* d_in, const int* in_sizes, int n_in,
                              void* d_out, int out_size, void* d_ws, size_t ws_size,
                              hipStream_t stream)
{
    const float* text    = (const float*)d_in[0];
    const float* audio   = (const float*)d_in[1];
    const float* visual  = (const float*)d_in[3];
    const float* W_text  = (const float*)d_in[4];
    const float* b_text  = (const float*)d_in[5];
    const float* W_audio = (const float*)d_in[6];
    const float* b_audio = (const float*)d_in[7];
    const float* W_vis   = (const float*)d_in[8];
    const float* b_vis   = (const float*)d_in[9];
    const float* in_w    = (const float*)d_in[10];
    const float* in_b    = (const float*)d_in[11];
    const float* conv_w  = (const float*)d_in[12];
    const float* conv_b  = (const float*)d_in[13];
    const float* xproj_w = (const float*)d_in[14];
    const float* dt_w    = (const float*)d_in[15];
    const float* dt_b    = (const float*)d_in[16];
    const float* Dskip   = (const float*)d_in[17];
    const float* conv_wB = (const float*)d_in[18];
    const float* conv_bB = (const float*)d_in[19];
    const float* xprojB  = (const float*)d_in[20];
    const float* dt_wB   = (const float*)d_in[21];
    const float* dt_bB   = (const float*)d_in[22];
    const float* DskipB  = (const float*)d_in[23];
    const float* out_w   = (const float*)d_in[24];
    const float* out_b   = (const float*)d_in[25];
    const float* fc1_w   = (const float*)d_in[26];
    const float* fc1_b   = (const float*)d_in[27];
    const float* fc2_w   = (const float*)d_in[28];
    const float* fc2_b   = (const float*)d_in[29];
    float* out           = (float*)d_out;

    // ---- workspace carve ----
    ushort_t* wsu = (ushort_t*)d_ws;
    size_t off = 0;
    auto alloc = [&](size_t n) { ushort_t* p = wsu + off; off += n; return p; };
    ushort_t* t_bf   = alloc(12582912);
    ushort_t* a_bf   = alloc(8388608);
    ushort_t* v_bf   = alloc(4194304);
    ushort_t* Wt_bf  = alloc(393216);
    ushort_t* Wa_bf  = alloc(262144);
    ushort_t* Wv_bf  = alloc(131072);
    ushort_t* inw_bf = alloc(2097152);    // [2][2048][512]
    ushort_t* xpf_bf = alloc(131072);     // [2][64][1024]
    ushort_t* dwf_bf = alloc(65536);      // [2][1024][32]
    ushort_t* xpb_bf = alloc(131072);
    ushort_t* dwb_bf = alloc(65536);
    ushort_t* ow_bf  = alloc(1048576);    // [2][512][1024]
    ushort_t* f1_bf  = alloc(131072);     // [256][512]
    ushort_t* b_h    = alloc(8388608);    // [M][512]
    ushort_t* b_xcf  = alloc(16777216);   // [M][1024]
    ushort_t* b_xcb  = alloc(16777216);
    ushort_t* b_szy  = alloc(16777216);   // silu(z), then y in-place
    ushort_t* b_dblf = alloc(524288);     // [M][32]
    ushort_t* b_dblb = alloc(524288);
    ushort_t* b_hid  = alloc(4194304);    // [M][256]
    float* b_bcf = (float*)(wsu + off); off += 2 * MTOT;
    float* b_bcb = (float*)(wsu + off); off += 2 * MTOT;
    (void)ws_size;

    // ---- conversions ----
    CvtArgs ca;
    const float* srcs[13] = { text, audio, visual, W_text, W_audio, W_vis,
                              in_w, xproj_w, dt_w, xprojB, dt_wB, out_w, fc1_w };
    ushort_t* dsts[13] = { t_bf, a_bf, v_bf, Wt_bf, Wa_bf, Wv_bf,
                           inw_bf, xpf_bf, dwf_bf, xpb_bf, dwb_bf, ow_bf, f1_bf };
    const int ns[13] = { 12582912, 8388608, 4194304, 393216, 262144, 131072,
                         2097152, 131072, 65536, 131072, 65536, 1048576, 131072 };
    for (int i = 0; i < 13; ++i) { ca.src[i] = srcs[i]; ca.dst[i] = dsts[i]; ca.n[i] = ns[i]; }
    cvt_k<<<dim3(192, 13), 256, 0, stream>>>(ca);

    const dim3 blk(256);
    // modality projections (relu) -> reps staged in xcf/xcb/szy (ldc=512)
    mgemm_k<1><<<dim3(4, 128), blk, 0, stream>>>(
        t_bf, 768, Wt_bf, 768, b_text, b_xcf, 512, 768,
        nullptr, nullptr, nullptr, nullptr, nullptr, nullptr);
    mgemm_k<1><<<dim3(4, 128), blk, 0, stream>>>(
        a_bf, 512, Wa_bf, 512, b_audio, b_xcb, 512, 512,
        nullptr, nullptr, nullptr, nullptr, nullptr, nullptr);
    mgemm_k<1><<<dim3(4, 128), blk, 0, stream>>>(
        v_bf, 256, Wv_bf, 256, b_vis, b_szy, 512, 256,
        nullptr, nullptr, nullptr, nullptr, nullptr, nullptr);
    fuseh_k<<<MTOT / 4, blk, 0, stream>>>(b_xcf, b_xcb, b_szy, b_h);

    for (int l = 0; l < 2; ++l) {
        mgemm_k<2><<<dim3(16, 128), blk, 0, stream>>>(
            b_h, 512, inw_bf + (size_t)l * 1048576, 512, in_b + l * 2048,
            b_xcf, 1024, 512,
            conv_w + l * 4096, conv_b + l * 1024,
            conv_wB + l * 4096, conv_bB + l * 1024, b_xcb, b_szy);
        dbl_k<<<dim3(256, 2), blk, 0, stream>>>(
            b_xcf, b_xcb,
            xpf_bf + (size_t)l * 65536, xpb_bf + (size_t)l * 65536,
            b_dblf, b_dblb, b_bcf, b_bcb);
        dty_k<<<dim3(16, 128), blk, 0, stream>>>(
            b_dblf, b_dblb,
            dwf_bf + (size_t)l * 32768, dwb_bf + (size_t)l * 32768,
            dt_b + l * 1024, dt_bB + l * 1024,
            Dskip + l * 1024, DskipB + l * 1024,
            b_bcf, b_bcb, b_xcf, b_xcb, b_szy);
        mgemm_k<0><<<dim3(4, 128), blk, 0, stream>>>(
            b_szy, 1024, ow_bf + (size_t)l * 524288, 1024, out_b + l * 512,
            b_h, 512, 1024,
            nullptr, nullptr, nullptr, nullptr, nullptr, nullptr);
    }

    mgemm_k<1><<<dim3(2, 128), blk, 0, stream>>>(
        b_h, 512, f1_bf, 512, fc1_b, b_hid, 256, 512,
        nullptr, nullptr, nullptr, nullptr, nullptr, nullptr);
    head_k<<<MTOT / 4, blk, 0, stream>>>(b_hid, fc2_w, fc2_b, out);
}

// Round 7
// 746.952 us; speedup vs baseline: 3.5388x; 1.0151x over previous
//
#include <hip/hip_runtime.h>
#include <hip/hip_bf16.h>

#define MTOT 16384      // B*T tokens; whole net is per-token
#define DI_ 1024

typedef __attribute__((ext_vector_type(8))) short bfrag;   // 8 bf16
typedef __attribute__((ext_vector_type(4))) float ffrag;   // 4 f32 acc
typedef unsigned short ushort_t;

__device__ __forceinline__ float us2f(ushort_t u) {
    union { float f; unsigned int i; } c; c.i = ((unsigned int)u) << 16; return c.f;
}
__device__ __forceinline__ ushort_t f2us(float f) {
    __hip_bfloat16 b = __float2bfloat16(f);
    return *(ushort_t*)&b;
}
__device__ __forceinline__ float silu_f(float x) {
    return x * __builtin_amdgcn_rcpf(1.0f + __expf(-x));
}
__device__ __forceinline__ float softplus_f(float x) {
    return fmaxf(x, 0.0f) + __logf(1.0f + __expf(-fabsf(x)));
}
__device__ __forceinline__ void glds16(const ushort_t* g, ushort_t* l) {
    __builtin_amdgcn_global_load_lds(
        (const __attribute__((address_space(1))) void*)g,
        (__attribute__((address_space(3))) void*)l, 16, 0, 0);
}
__device__ __forceinline__ uint4 pack8(const float* v) {
    union { uint4 u; ushort_t s[8]; } r;
#pragma unroll
    for (int e = 0; e < 8; ++e) r.s[e] = f2us(v[e]);
    return r.u;
}

// ---------------------------------------------------------------------------
// f32 -> bf16 conversion for 13 arrays in one launch
// ---------------------------------------------------------------------------
struct CvtArgs { const float* src[13]; ushort_t* dst[13]; int n[13]; };
__global__ __launch_bounds__(256) void cvt_k(CvtArgs a)
{
    const int id = blockIdx.y;
    const int n4 = a.n[id] >> 2;
    const float* s = a.src[id];
    ushort_t* d = a.dst[id];
    const int stride = gridDim.x * blockDim.x;
    for (int i = blockIdx.x * blockDim.x + threadIdx.x; i < n4; i += stride) {
        float4 v = *(const float4*)(s + (size_t)i * 4);
        ushort_t o[4] = { f2us(v.x), f2us(v.y), f2us(v.z), f2us(v.w) };
        *(uint2*)(d + (size_t)i * 4) = *(uint2*)o;
    }
}

// ---------------------------------------------------------------------------
// MFMA NT GEMM 128x128, BK=32, 4 waves. 3-buffer depth-3 global_load_lds
// pipeline with COUNTED vmcnt (T4): tiles t,t+1,t+2 in flight; per iteration
// wait vmcnt(8) (tile t done), compute, barrier, restage buf with tile t+3.
// Drain peels to vmcnt(4)/vmcnt(0). Requires NT >= 3 (all K >= 96 here).
// Epilogue: LDS f32 transpose -> coalesced uint4 bf16 stores.
// EPI: 0 none, 1 relu, 2 in_w split (xcf/xcb silu-conv | silu(z))
// ---------------------------------------------------------------------------
template <int EPI>
__global__ __launch_bounds__(256) void mgemm_k(
    const ushort_t* __restrict__ A, int lda,
    const ushort_t* __restrict__ W, int ldw,
    const float* __restrict__ bias,
    ushort_t* __restrict__ C, int ldc, int K,
    const float* __restrict__ cwf, const float* __restrict__ cbf,
    const float* __restrict__ cwb, const float* __restrict__ cbb,
    ushort_t* __restrict__ out2, ushort_t* __restrict__ out3)
{
    constexpr int BM = 128, BN = 128, TP = 132;
    constexpr int BUF = 8192;              // ushorts per staging buffer (16 KB)
    __shared__ char smem[49152];           // 3 buffers; epilogue reuses 16896B
    ushort_t* SMu = (ushort_t*)smem;

    const int tid = threadIdx.x;
    const int lane = tid & 63;
    const int w = tid >> 6;
    const int wr = w >> 1, wc = w & 1;
    const int m0 = blockIdx.y * BM, n0 = blockIdx.x * BN;

    // staging: 16 wave-loads of 1KB (lw = w*4+q); loads 0..7 = A, 8..15 = W
    const ushort_t* gsrc[4];
    ushort_t* ldst[4];
#pragma unroll
    for (int q = 0; q < 4; ++q) {
        const int lw = w * 4 + q;
        const int c = lw * 64 + lane;
        ldst[q] = SMu + (size_t)lw * 512;
        if (c < BM * 4) {
            const int row = c >> 2, slot = c & 3;
            const int gslot = slot ^ ((row >> 1) & 3);
            gsrc[q] = A + (size_t)(m0 + row) * lda + gslot * 8;
        } else {
            const int c2 = c - BM * 4;
            const int row = c2 >> 2, slot = c2 & 3;
            const int gslot = slot ^ ((row >> 1) & 3);
            gsrc[q] = W + (size_t)(n0 + row) * ldw + gslot * 8;
        }
    }

    // fragment ds_read offsets (swizzle matches staging)
    const int kg = lane >> 4;
    int aoff[4], boff[4];
#pragma unroll
    for (int i = 0; i < 4; ++i) {
        const int r = wr * 64 + i * 16 + (lane & 15);
        aoff[i] = r * 32 + ((kg ^ ((r >> 1) & 3)) * 8);
        const int rw = wc * 64 + i * 16 + (lane & 15);
        boff[i] = BM * 32 + rw * 32 + ((kg ^ ((rw >> 1) & 3)) * 8);
    }

    ffrag acc[4][4];
#pragma unroll
    for (int i = 0; i < 4; ++i)
#pragma unroll
        for (int j = 0; j < 4; ++j) acc[i][j] = (ffrag){0.f, 0.f, 0.f, 0.f};

    const int NT = K >> 5;
    // prologue: stage tiles 0,1,2 into buffers 0,1,2 (12 loads in flight)
#pragma unroll
    for (int q = 0; q < 4; ++q) glds16(gsrc[q], ldst[q]);
#pragma unroll
    for (int q = 0; q < 4; ++q) glds16(gsrc[q] + 32, ldst[q] + BUF);
#pragma unroll
    for (int q = 0; q < 4; ++q) glds16(gsrc[q] + 64, ldst[q] + 2 * BUF);

    int cur = 0;
    for (int t = 0; t < NT; ++t) {
        if (t + 2 < NT)      asm volatile("s_waitcnt vmcnt(8)" ::: "memory");
        else if (t + 1 < NT) asm volatile("s_waitcnt vmcnt(4)" ::: "memory");
        else                 asm volatile("s_waitcnt vmcnt(0)" ::: "memory");
        __builtin_amdgcn_s_barrier();
        __builtin_amdgcn_sched_barrier(0);

        const ushort_t* Sb = SMu + cur * BUF;
        bfrag af[4], bw[4];
#pragma unroll
        for (int i = 0; i < 4; ++i) af[i] = *(const bfrag*)(Sb + aoff[i]);
#pragma unroll
        for (int j = 0; j < 4; ++j) bw[j] = *(const bfrag*)(Sb + boff[j]);
#pragma unroll
        for (int i = 0; i < 4; ++i)
#pragma unroll
            for (int j = 0; j < 4; ++j)
                acc[i][j] = __builtin_amdgcn_mfma_f32_16x16x32_bf16(
                    af[i], bw[j], acc[i][j], 0, 0, 0);

        __builtin_amdgcn_s_barrier();         // all waves done reading buf cur
        __builtin_amdgcn_sched_barrier(0);
        if (t + 3 < NT) {
#pragma unroll
            for (int q = 0; q < 4; ++q)
                glds16(gsrc[q] + (t + 3) * 32, ldst[q] + cur * BUF);
        }
        cur = (cur == 2) ? 0 : cur + 1;
    }

    float bj[4];
#pragma unroll
    for (int j = 0; j < 4; ++j) {
        const int col = n0 + wc * 64 + j * 16 + (lane & 15);
        bj[j] = bias ? bias[col] : 0.0f;
    }

    float* lt = (float*)smem;
    const bool lo = (EPI != 2) || (n0 < DI_);

    for (int i = 0; i < 4; ++i) {            // 32-row chunks
        __syncthreads();
#pragma unroll
        for (int j = 0; j < 4; ++j)
#pragma unroll
            for (int r = 0; r < 4; ++r)
                lt[(wr * 16 + (lane >> 4) * 4 + r) * TP + wc * 64 + j * 16 + (lane & 15)]
                    = acc[i][j][r] + bj[j];
        __syncthreads();
#pragma unroll
        for (int p = 0; p < 2; ++p) {
            const int lrow = p * 16 + (tid >> 4);
            const int cg = tid & 15;
            const int grow = m0 + (lrow >> 4) * 64 + i * 16 + (lrow & 15);
            const int gc = n0 + cg * 8;
            float4 v0 = *(float4*)&lt[lrow * TP + cg * 8];
            float4 v1 = *(float4*)&lt[lrow * TP + cg * 8 + 4];
            float v[8] = { v0.x, v0.y, v0.z, v0.w, v1.x, v1.y, v1.z, v1.w };
            if (EPI == 0) {
                *(uint4*)(C + (size_t)grow * ldc + gc) = pack8(v);
            } else if (EPI == 1) {
                float rv[8];
#pragma unroll
                for (int e = 0; e < 8; ++e) rv[e] = fmaxf(v[e], 0.0f);
                *(uint4*)(C + (size_t)grow * ldc + gc) = pack8(rv);
            } else {
                if (lo) {
                    float vf[8], vb[8];
#pragma unroll
                    for (int e = 0; e < 8; ++e) {
                        const int c = gc + e;
                        vf[e] = silu_f(v[e] * cwf[c * 4 + 3] + cbf[c]);
                        vb[e] = silu_f(v[e] * cwb[c * 4 + 3] + cbb[c]);
                    }
                    *(uint4*)(C + (size_t)grow * DI_ + gc)    = pack8(vf);
                    *(uint4*)(out2 + (size_t)grow * DI_ + gc) = pack8(vb);
                } else {
                    float vz[8];
#pragma unroll
                    for (int e = 0; e < 8; ++e) vz[e] = silu_f(v[e]);
                    *(uint4*)(out3 + (size_t)grow * DI_ + (gc - DI_)) = pack8(vz);
                }
            }
        }
    }
}

// ---------------------------------------------------------------------------
// dbl GEMM 64x64 (K=1024, NT=32), fwd+bwd via blockIdx.y, depth-3 counted
// pipeline. dbl = xc @ xproj^T; stores ONLY cols 0..31 (dt_in); fuses
// bc[r] = sum_s dbl[r,32+s]*dbl[r,48+s] (from f32 acc).
// ---------------------------------------------------------------------------
__global__ __launch_bounds__(256) void dbl_k(
    const ushort_t* __restrict__ Afwd, const ushort_t* __restrict__ Abwd,
    const ushort_t* __restrict__ Wfwd, const ushort_t* __restrict__ Wbwd,
    ushort_t* __restrict__ Dfwd, ushort_t* __restrict__ Dbwd,
    float* __restrict__ bcFo, float* __restrict__ bcBo)
{
    constexpr int BM = 64, TP = 36;
    constexpr int BUF = 4096;             // ushorts per buffer (8 KB)
    __shared__ char smem[24576];          // 3 buffers; epilogue lt = 4608B
    ushort_t* SMu = (ushort_t*)smem;

    const int tid = threadIdx.x;
    const int lane = tid & 63;
    const int w = tid >> 6;
    const int wr = w >> 1, wc = w & 1;
    const int m0 = blockIdx.x * 64;
    const ushort_t* A = blockIdx.y ? Abwd : Afwd;
    const ushort_t* W = blockIdx.y ? Wbwd : Wfwd;
    ushort_t* D = blockIdx.y ? Dbwd : Dfwd;
    float* bco = blockIdx.y ? bcBo : bcFo;

    const ushort_t* gsrc[2];
    ushort_t* ldst[2];
#pragma unroll
    for (int q = 0; q < 2; ++q) {
        const int lw = w * 2 + q;
        const int c = lw * 64 + lane;
        ldst[q] = SMu + (size_t)lw * 512;
        if (c < BM * 4) {
            const int row = c >> 2, slot = c & 3;
            const int gslot = slot ^ ((row >> 1) & 3);
            gsrc[q] = A + (size_t)(m0 + row) * 1024 + gslot * 8;
        } else {
            const int c2 = c - BM * 4;
            const int row = c2 >> 2, slot = c2 & 3;
            const int gslot = slot ^ ((row >> 1) & 3);
            gsrc[q] = W + (size_t)row * 1024 + gslot * 8;
        }
    }

    const int kg = lane >> 4;
    int aoff[2], boff[2];
#pragma unroll
    for (int i = 0; i < 2; ++i) {
        const int r = wr * 32 + i * 16 + (lane & 15);
        aoff[i] = r * 32 + ((kg ^ ((r >> 1) & 3)) * 8);
        const int rw = wc * 32 + i * 16 + (lane & 15);
        boff[i] = BM * 32 + rw * 32 + ((kg ^ ((rw >> 1) & 3)) * 8);
    }

    ffrag acc[2][2];
#pragma unroll
    for (int i = 0; i < 2; ++i)
#pragma unroll
        for (int j = 0; j < 2; ++j) acc[i][j] = (ffrag){0.f, 0.f, 0.f, 0.f};

    // prologue: tiles 0,1,2 (6 loads in flight)
#pragma unroll
    for (int q = 0; q < 2; ++q) glds16(gsrc[q], ldst[q]);
#pragma unroll
    for (int q = 0; q < 2; ++q) glds16(gsrc[q] + 32, ldst[q] + BUF);
#pragma unroll
    for (int q = 0; q < 2; ++q) glds16(gsrc[q] + 64, ldst[q] + 2 * BUF);

    int cur = 0;
    for (int t = 0; t < 32; ++t) {
        if (t + 2 < 32)      asm volatile("s_waitcnt vmcnt(4)" ::: "memory");
        else if (t + 1 < 32) asm volatile("s_waitcnt vmcnt(2)" ::: "memory");
        else                 asm volatile("s_waitcnt vmcnt(0)" ::: "memory");
        __builtin_amdgcn_s_barrier();
        __builtin_amdgcn_sched_barrier(0);

        const ushort_t* Sb = SMu + cur * BUF;
        bfrag af[2], bw[2];
#pragma unroll
        for (int i = 0; i < 2; ++i) af[i] = *(const bfrag*)(Sb + aoff[i]);
#pragma unroll
        for (int j = 0; j < 2; ++j) bw[j] = *(const bfrag*)(Sb + boff[j]);
#pragma unroll
        for (int i = 0; i < 2; ++i)
#pragma unroll
            for (int j = 0; j < 2; ++j)
                acc[i][j] = __builtin_amdgcn_mfma_f32_16x16x32_bf16(
                    af[i], bw[j], acc[i][j], 0, 0, 0);

        __builtin_amdgcn_s_barrier();
        __builtin_amdgcn_sched_barrier(0);
        if (t + 3 < 32) {
#pragma unroll
            for (int q = 0; q < 2; ++q)
                glds16(gsrc[q] + (t + 3) * 32, ldst[q] + cur * BUF);
        }
        cur = (cur == 2) ? 0 : cur + 1;
    }

    // bc from f32 acc: wc==1 waves own cols 32..47 (j=0) and 48..63 (j=1)
    if (wc == 1) {
#pragma unroll
        for (int i = 0; i < 2; ++i)
#pragma unroll
            for (int r = 0; r < 4; ++r) {
                float p = acc[i][0][r] * acc[i][1][r];
                p += __shfl_xor(p, 1, 64);
                p += __shfl_xor(p, 2, 64);
                p += __shfl_xor(p, 4, 64);
                p += __shfl_xor(p, 8, 64);
                if ((lane & 15) == 0)
                    bco[m0 + wr * 32 + i * 16 + (lane >> 4) * 4 + r] = p;
            }
    }

    // transpose-store cols 0..31 (wc==0 waves hold them)
    float* lt = (float*)smem;
    for (int i = 0; i < 2; ++i) {
        __syncthreads();
        if (wc == 0) {
#pragma unroll
            for (int j = 0; j < 2; ++j)
#pragma unroll
                for (int r = 0; r < 4; ++r)
                    lt[(wr * 16 + (lane >> 4) * 4 + r) * TP + j * 16 + (lane & 15)]
                        = acc[i][j][r];
        }
        __syncthreads();
        const int lrow = tid >> 3;      // 0..31
        const int cg = tid & 7;
        if (cg < 4) {
            const int grow = m0 + (lrow >> 4) * 32 + i * 16 + (lrow & 15);
            float4 v0 = *(float4*)&lt[lrow * TP + cg * 8];
            float4 v1 = *(float4*)&lt[lrow * TP + cg * 8 + 4];
            float v[8] = { v0.x, v0.y, v0.z, v0.w, v1.x, v1.y, v1.z, v1.w };
            *(uint4*)(D + (size_t)grow * 32 + cg * 8) = pack8(v);
        }
    }
}

// ---------------------------------------------------------------------------
// dt GEMM (K=32, fwd+bwd, no LDS staging) + SSM epilogue with LDS transpose
// so all xcf/xcb/szy traffic is coalesced uint4.
//   y = (xcf*(sp(dtf)*bcf + Dpf) + xcb*(sp(dtb)*bcb + Dpb)) * sz   (in-place)
// Block: 128 rows x 64 cols, grid (16, 128).
// ---------------------------------------------------------------------------
__global__ __launch_bounds__(256) void dty_k(
    const ushort_t* __restrict__ dblf, const ushort_t* __restrict__ dblb,
    const ushort_t* __restrict__ wtf,  const ushort_t* __restrict__ wtb,
    const float* __restrict__ dbf, const float* __restrict__ dbb,
    const float* __restrict__ Dpf, const float* __restrict__ Dpb,
    const float* __restrict__ bcf, const float* __restrict__ bcb,
    const ushort_t* __restrict__ xcf, const ushort_t* __restrict__ xcb,
    ushort_t* szy)
{
    __shared__ float ltF[64 * 68];
    __shared__ float ltB[64 * 68];
    const int tid = threadIdx.x, lane = tid & 63, w = tid >> 6;
    const int m0 = blockIdx.y * 128, n0 = blockIdx.x * 64;
    const int koff = (lane >> 4) * 8;

    bfrag aF[2], aB[2], wF[4], wB[4];
#pragma unroll
    for (int i = 0; i < 2; ++i) {
        const int row = m0 + w * 32 + i * 16 + (lane & 15);
        aF[i] = *(const bfrag*)(dblf + (size_t)row * 32 + koff);
        aB[i] = *(const bfrag*)(dblb + (size_t)row * 32 + koff);
    }
#pragma unroll
    for (int j = 0; j < 4; ++j) {
        const int col = n0 + j * 16 + (lane & 15);
        wF[j] = *(const bfrag*)(wtf + (size_t)col * 32 + koff);
        wB[j] = *(const bfrag*)(wtb + (size_t)col * 32 + koff);
    }
    ffrag accF[2][4], accB[2][4];
#pragma unroll
    for (int i = 0; i < 2; ++i)
#pragma unroll
        for (int j = 0; j < 4; ++j) {
            ffrag z = (ffrag){0.f, 0.f, 0.f, 0.f};
            accF[i][j] = __builtin_amdgcn_mfma_f32_16x16x32_bf16(aF[i], wF[j], z, 0, 0, 0);
            z = (ffrag){0.f, 0.f, 0.f, 0.f};
            accB[i][j] = __builtin_amdgcn_mfma_f32_16x16x32_bf16(aB[i], wB[j], z, 0, 0, 0);
        }

    float dbfj[4], dbbj[4];
#pragma unroll
    for (int j = 0; j < 4; ++j) {
        const int c = n0 + j * 16 + (lane & 15);
        dbfj[j] = dbf[c]; dbbj[j] = dbb[c];
    }

    for (int i = 0; i < 2; ++i) {
        __syncthreads();
#pragma unroll
        for (int j = 0; j < 4; ++j)
#pragma unroll
            for (int r = 0; r < 4; ++r) {
                const int lr = w * 16 + (lane >> 4) * 4 + r;
                const int cc = j * 16 + (lane & 15);
                ltF[lr * 68 + cc] = accF[i][j][r] + dbfj[j];
                ltB[lr * 68 + cc] = accB[i][j][r] + dbbj[j];
            }
        __syncthreads();
        const int lrow = tid >> 2;      // 0..63
        const int cg = tid & 3;         // x16 cols
        const int grow = m0 + (lrow >> 4) * 32 + i * 16 + (lrow & 15);
        const float vbcf = bcf[grow], vbcb = bcb[grow];
#pragma unroll
        for (int h = 0; h < 2; ++h) {
            const int c0 = cg * 16 + h * 8;
            const int gc = n0 + c0;
            const size_t base = (size_t)grow * DI_ + gc;
            uint4 xf4 = *(const uint4*)(xcf + base);
            uint4 xb4 = *(const uint4*)(xcb + base);
            uint4 sz4 = *(const uint4*)(szy + base);
            const ushort_t* xf = (const ushort_t*)&xf4;
            const ushort_t* xb = (const ushort_t*)&xb4;
            const ushort_t* sz = (const ushort_t*)&sz4;
            float v[8];
#pragma unroll
            for (int e = 0; e < 8; ++e) {
                const float dtf = softplus_f(ltF[lrow * 68 + c0 + e]);
                const float dtb = softplus_f(ltB[lrow * 68 + c0 + e]);
                const float vf = us2f(xf[e]) * (dtf * vbcf + Dpf[gc + e]);
                const float vb = us2f(xb[e]) * (dtb * vbcb + Dpb[gc + e]);
                v[e] = (vf + vb) * us2f(sz[e]);
            }
            *(uint4*)(szy + base) = pack8(v);
        }
    }
}

// ---------------------------------------------------------------------------
// Modality fusion: 4 tokens/block, one wave per token.
// ---------------------------------------------------------------------------
__global__ __launch_bounds__(256) void fuseh_k(
    const ushort_t* __restrict__ r0, const ushort_t* __restrict__ r1,
    const ushort_t* __restrict__ r2, ushort_t* __restrict__ h)
{
    const int t = blockIdx.x * 4 + (threadIdx.x >> 6);
    const int lane = threadIdx.x & 63;
    uint4 raw0 = *(const uint4*)(r0 + (size_t)t * 512 + lane * 8);
    uint4 raw1 = *(const uint4*)(r1 + (size_t)t * 512 + lane * 8);
    uint4 raw2 = *(const uint4*)(r2 + (size_t)t * 512 + lane * 8);
    const ushort_t* p0 = (const ushort_t*)&raw0;
    const ushort_t* p1 = (const ushort_t*)&raw1;
    const ushort_t* p2 = (const ushort_t*)&raw2;
    float v0[8], v1[8], v2[8];
    float s0 = 0.f, s1 = 0.f, s2 = 0.f;
#pragma unroll
    for (int j = 0; j < 8; ++j) {
        v0[j] = us2f(p0[j]); v1[j] = us2f(p1[j]); v2[j] = us2f(p2[j]);
        s0 += v0[j] * v0[j]; s1 += v1[j] * v1[j]; s2 += v2[j] * v2[j];
    }
#pragma unroll
    for (int m = 32; m >= 1; m >>= 1) {
        s0 += __shfl_xor(s0, m, 64);
        s1 += __shfl_xor(s1, m, 64);
        s2 += __shfl_xor(s2, m, 64);
    }
    const float n0 = sqrtf(s0), n1 = sqrtf(s1), n2 = sqrtf(s2);
    const float mx = fmaxf(n0, fmaxf(n1, n2));
    const float e0 = __expf(n0 - mx), e1 = __expf(n1 - mx), e2 = __expf(n2 - mx);
    const float inv = __builtin_amdgcn_rcpf(e0 + e1 + e2);
    const float w0 = e0 * inv / fmaxf(n0, 1e-12f);
    const float w1 = e1 * inv / fmaxf(n1, 1e-12f);
    const float w2 = e2 * inv / fmaxf(n2, 1e-12f);
    float o[8];
#pragma unroll
    for (int j = 0; j < 8; ++j) o[j] = w0 * v0[j] + w1 * v1[j] + w2 * v2[j];
    *(uint4*)(h + (size_t)t * 512 + lane * 8) = pack8(o);
}

// ---------------------------------------------------------------------------
// Head: logits = tanh(hid @ fc2^T + b), log_softmax(2). OUTPUT FLOAT32.
// ---------------------------------------------------------------------------
__global__ __launch_bounds__(256) void head_k(
    const ushort_t* __restrict__ hid, const float* __restrict__ fc2w,
    const float* __restrict__ fc2b, float* __restrict__ out)
{
    const int tid = threadIdx.x;
    const int lane = tid & 63;
    const int t = blockIdx.x * 4 + (tid >> 6);
    uint2 raw = *(const uint2*)(hid + (size_t)t * 256 + lane * 4);
    const ushort_t* hp = (const ushort_t*)&raw;
    float4 w0 = *(const float4*)(fc2w + lane * 4);
    float4 w1 = *(const float4*)(fc2w + 256 + lane * 4);
    float h0 = us2f(hp[0]), h1 = us2f(hp[1]), h2 = us2f(hp[2]), h3 = us2f(hp[3]);
    float d0 = h0 * w0.x + h1 * w0.y + h2 * w0.z + h3 * w0.w;
    float d1 = h0 * w1.x + h1 * w1.y + h2 * w1.z + h3 * w1.w;
#pragma unroll
    for (int m = 32; m >= 1; m >>= 1) {
        d0 += __shfl_xor(d0, m, 64);
        d1 += __shfl_xor(d1, m, 64);
    }
    if (lane == 0) {
        const float l0 = tanhf(d0 + fc2b[0]);
        const float l1 = tanhf(d1 + fc2b[1]);
        const float mx = fmaxf(l0, l1);
        const float lse = mx + __logf(__expf(l0 - mx) + __expf(l1 - mx));
        out[(size_t)t * 2 + 0] = l0 - lse;
        out[(size_t)t * 2 + 1] = l1 - lse;
    }
}

// ---------------------------------------------------------------------------
extern "C" void kernel_launch(void* const* d_in, const int* in_sizes, int n_in,
                              void* d_out, int out_size, void* d_ws, size_t ws_size,
                              hipStream_t stream)
{
    const float* text    = (const float*)d_in[0];
    const float* audio   = (const float*)d_in[1];
    const float* visual  = (const float*)d_in[3];
    const float* W_text  = (const float*)d_in[4];
    const float* b_text  = (const float*)d_in[5];
    const float* W_audio = (const float*)d_in[6];
    const float* b_audio = (const float*)d_in[7];
    const float* W_vis   = (const float*)d_in[8];
    const float* b_vis   = (const float*)d_in[9];
    const float* in_w    = (const float*)d_in[10];
    const float* in_b    = (const float*)d_in[11];
    const float* conv_w  = (const float*)d_in[12];
    const float* conv_b  = (const float*)d_in[13];
    const float* xproj_w = (const float*)d_in[14];
    const float* dt_w    = (const float*)d_in[15];
    const float* dt_b    = (const float*)d_in[16];
    const float* Dskip   = (const float*)d_in[17];
    const float* conv_wB = (const float*)d_in[18];
    const float* conv_bB = (const float*)d_in[19];
    const float* xprojB  = (const float*)d_in[20];
    const float* dt_wB   = (const float*)d_in[21];
    const float* dt_bB   = (const float*)d_in[22];
    const float* DskipB  = (const float*)d_in[23];
    const float* out_w   = (const float*)d_in[24];
    const float* out_b   = (const float*)d_in[25];
    const float* fc1_w   = (const float*)d_in[26];
    const float* fc1_b   = (const float*)d_in[27];
    const float* fc2_w   = (const float*)d_in[28];
    const float* fc2_b   = (const float*)d_in[29];
    float* out           = (float*)d_out;

    // ---- workspace carve ----
    ushort_t* wsu = (ushort_t*)d_ws;
    size_t off = 0;
    auto alloc = [&](size_t n) { ushort_t* p = wsu + off; off += n; return p; };
    ushort_t* t_bf   = alloc(12582912);
    ushort_t* a_bf   = alloc(8388608);
    ushort_t* v_bf   = alloc(4194304);
    ushort_t* Wt_bf  = alloc(393216);
    ushort_t* Wa_bf  = alloc(262144);
    ushort_t* Wv_bf  = alloc(131072);
    ushort_t* inw_bf = alloc(2097152);    // [2][2048][512]
    ushort_t* xpf_bf = alloc(131072);     // [2][64][1024]
    ushort_t* dwf_bf = alloc(65536);      // [2][1024][32]
    ushort_t* xpb_bf = alloc(131072);
    ushort_t* dwb_bf = alloc(65536);
    ushort_t* ow_bf  = alloc(1048576);    // [2][512][1024]
    ushort_t* f1_bf  = alloc(131072);     // [256][512]
    ushort_t* b_h    = alloc(8388608);    // [M][512]
    ushort_t* b_xcf  = alloc(16777216);   // [M][1024]
    ushort_t* b_xcb  = alloc(16777216);
    ushort_t* b_szy  = alloc(16777216);   // silu(z), then y in-place
    ushort_t* b_dblf = alloc(524288);     // [M][32]
    ushort_t* b_dblb = alloc(524288);
    ushort_t* b_hid  = alloc(4194304);    // [M][256]
    float* b_bcf = (float*)(wsu + off); off += 2 * MTOT;
    float* b_bcb = (float*)(wsu + off); off += 2 * MTOT;
    (void)ws_size;

    // ---- conversions ----
    CvtArgs ca;
    const float* srcs[13] = { text, audio, visual, W_text, W_audio, W_vis,
                              in_w, xproj_w, dt_w, xprojB, dt_wB, out_w, fc1_w };
    ushort_t* dsts[13] = { t_bf, a_bf, v_bf, Wt_bf, Wa_bf, Wv_bf,
                           inw_bf, xpf_bf, dwf_bf, xpb_bf, dwb_bf, ow_bf, f1_bf };
    const int ns[13] = { 12582912, 8388608, 4194304, 393216, 262144, 131072,
                         2097152, 131072, 65536, 131072, 65536, 1048576, 131072 };
    for (int i = 0; i < 13; ++i) { ca.src[i] = srcs[i]; ca.dst[i] = dsts[i]; ca.n[i] = ns[i]; }
    cvt_k<<<dim3(192, 13), 256, 0, stream>>>(ca);

    const dim3 blk(256);
    // modality projections (relu) -> reps staged in xcf/xcb/szy (ldc=512)
    mgemm_k<1><<<dim3(4, 128), blk, 0, stream>>>(
        t_bf, 768, Wt_bf, 768, b_text, b_xcf, 512, 768,
        nullptr, nullptr, nullptr, nullptr, nullptr, nullptr);
    mgemm_k<1><<<dim3(4, 128), blk, 0, stream>>>(
        a_bf, 512, Wa_bf, 512, b_audio, b_xcb, 512, 512,
        nullptr, nullptr, nullptr, nullptr, nullptr, nullptr);
    mgemm_k<1><<<dim3(4, 128), blk, 0, stream>>>(
        v_bf, 256, Wv_bf, 256, b_vis, b_szy, 512, 256,
        nullptr, nullptr, nullptr, nullptr, nullptr, nullptr);
    fuseh_k<<<MTOT / 4, blk, 0, stream>>>(b_xcf, b_xcb, b_szy, b_h);

    for (int l = 0; l < 2; ++l) {
        mgemm_k<2><<<dim3(16, 128), blk, 0, stream>>>(
            b_h, 512, inw_bf + (size_t)l * 1048576, 512, in_b + l * 2048,
            b_xcf, 1024, 512,
            conv_w + l * 4096, conv_b + l * 1024,
            conv_wB + l * 4096, conv_bB + l * 1024, b_xcb, b_szy);
        dbl_k<<<dim3(256, 2), blk, 0, stream>>>(
            b_xcf, b_xcb,
            xpf_bf + (size_t)l * 65536, xpb_bf + (size_t)l * 65536,
            b_dblf, b_dblb, b_bcf, b_bcb);
        dty_k<<<dim3(16, 128), blk, 0, stream>>>(
            b_dblf, b_dblb,
            dwf_bf + (size_t)l * 32768, dwb_bf + (size_t)l * 32768,
            dt_b + l * 1024, dt_bB + l * 1024,
            Dskip + l * 1024, DskipB + l * 1024,
            b_bcf, b_bcb, b_xcf, b_xcb, b_szy);
        mgemm_k<0><<<dim3(4, 128), blk, 0, stream>>>(
            b_szy, 1024, ow_bf + (size_t)l * 524288, 1024, out_b + l * 512,
            b_h, 512, 1024,
            nullptr, nullptr, nullptr, nullptr, nullptr, nullptr);
    }

    mgemm_k<1><<<dim3(2, 128), blk, 0, stream>>>(
        b_h, 512, f1_bf, 512, fc1_b, b_hid, 256, 512,
        nullptr, nullptr, nullptr, nullptr, nullptr, nullptr);
    head_k<<<MTOT / 4, blk, 0, stream>>>(b_hid, fc2_w, fc2_b, out);
}

// Round 9
// 605.288 us; speedup vs baseline: 4.3670x; 1.2340x over previous
//
#include <hip/hip_runtime.h>
#include <hip/hip_bf16.h>

#define MTOT 16384
#define DI_ 1024
#define SKT ((size_t)MTOT * 32)   // kt32 ktile stride for M-row activations

typedef __attribute__((ext_vector_type(8))) short bfrag;   // 8 bf16
typedef __attribute__((ext_vector_type(4))) float ffrag;   // 4 f32 acc
typedef unsigned short ushort_t;

__device__ __forceinline__ float us2f(ushort_t u) {
    union { float f; unsigned int i; } c; c.i = ((unsigned int)u) << 16; return c.f;
}
__device__ __forceinline__ ushort_t f2us(float f) {
    __hip_bfloat16 b = __float2bfloat16(f);
    return *(ushort_t*)&b;
}
__device__ __forceinline__ float silu_f(float x) {
    return x * __builtin_amdgcn_rcpf(1.0f + __expf(-x));
}
__device__ __forceinline__ float softplus_f(float x) {
    return fmaxf(x, 0.0f) + __logf(1.0f + __expf(-fabsf(x)));
}
__device__ __forceinline__ void glds16(const ushort_t* g, ushort_t* l) {
    __builtin_amdgcn_global_load_lds(
        (const __attribute__((address_space(1))) void*)g,
        (__attribute__((address_space(3))) void*)l, 16, 0, 0);
}
__device__ __forceinline__ uint4 pack8(const float* v) {
    union { uint4 u; ushort_t s[8]; } r;
#pragma unroll
    for (int e = 0; e < 8; ++e) r.s[e] = f2us(v[e]);
    return r.u;
}

// ---------------------------------------------------------------------------
// f32 -> bf16 conversion, optionally into kt32 layout ([k/32][m][32]).
// kq = K/4 (0 => plain row-major copy); r32 = R*32 (ktile element stride).
// ---------------------------------------------------------------------------
struct CvtArgs { const float* src[13]; ushort_t* dst[13]; int n[13]; int kq[13]; int r32[13]; };
__global__ __launch_bounds__(256) void cvt_k(CvtArgs a)
{
    const int id = blockIdx.y;
    const int n4 = a.n[id] >> 2;
    const int kq = a.kq[id];
    const int r32 = a.r32[id];
    const float* s = a.src[id];
    ushort_t* d = a.dst[id];
    const int stride = gridDim.x * blockDim.x;
    for (int i = blockIdx.x * blockDim.x + threadIdx.x; i < n4; i += stride) {
        float4 v = *(const float4*)(s + (size_t)i * 4);
        ushort_t o[4] = { f2us(v.x), f2us(v.y), f2us(v.z), f2us(v.w) };
        size_t dst;
        if (kq == 0) {
            dst = (size_t)i * 4;
        } else {
            const int m = i / kq;
            const int kk = (i - m * kq) * 4;
            dst = (size_t)(kk >> 5) * (size_t)r32 + (size_t)m * 32 + (kk & 31);
        }
        *(uint2*)(d + dst) = *(uint2*)o;
    }
}

// ---------------------------------------------------------------------------
// MFMA NT GEMM 128x128, BK=32, 4 waves. A and W in kt32 layout (per-ktile
// element strides sA, sW) => every glds reads 1 KB CONTIGUOUS. Depth-3
// counted-vmcnt pipeline. Epilogue: LDS f32 transpose ->
//   EPI 0: kt32 store (stride sC)      (out_w -> b_h)
//   EPI 1: row-major relu store (ldc)  (projections, fc1)
//   EPI 2: in_w split, kt32 stores (xcf/xcb silu-conv | silu(z) -> out3)
// ---------------------------------------------------------------------------
template <int EPI>
__global__ __launch_bounds__(256) void mgemm_k(
    const ushort_t* __restrict__ A, int sA,
    const ushort_t* __restrict__ W, int sW,
    const float* __restrict__ bias,
    ushort_t* __restrict__ C, int ldc, int sC, int K,
    const float* __restrict__ cwf, const float* __restrict__ cbf,
    const float* __restrict__ cwb, const float* __restrict__ cbb,
    ushort_t* __restrict__ out2, ushort_t* __restrict__ out3)
{
    constexpr int BM = 128, BN = 128, TP = 132;
    constexpr int BUF = 8192;              // ushorts per staging buffer (16 KB)
    __shared__ char smem[49152];           // 3 buffers; epilogue reuses 16896B
    ushort_t* SMu = (ushort_t*)smem;

    const int tid = threadIdx.x;
    const int lane = tid & 63;
    const int w = tid >> 6;
    const int wr = w >> 1, wc = w & 1;
    const int m0 = blockIdx.y * BM, n0 = blockIdx.x * BN;

    // staging: 16 wave-loads of 1KB; loads 0..7 = A-tile, 8..15 = W-tile.
    // kt32: tile for K-step t lives at [m0..m0+127][0..31] of slab t.
    const ushort_t* gsrc[4];
    ushort_t* ldst[4];
    int gstr[4];
#pragma unroll
    for (int q = 0; q < 4; ++q) {
        const int lw = w * 4 + q;
        const int c = lw * 64 + lane;
        ldst[q] = SMu + (size_t)lw * 512;
        if (c < BM * 4) {
            const int row = c >> 2, slot = c & 3;
            const int gslot = slot ^ ((row >> 1) & 3);
            gsrc[q] = A + (size_t)(m0 + row) * 32 + gslot * 8;
            gstr[q] = sA;
        } else {
            const int c2 = c - BM * 4;
            const int row = c2 >> 2, slot = c2 & 3;
            const int gslot = slot ^ ((row >> 1) & 3);
            gsrc[q] = W + (size_t)(n0 + row) * 32 + gslot * 8;
            gstr[q] = sW;
        }
    }

    // fragment ds_read offsets (k-slot swizzle matches staging)
    const int kg = lane >> 4;
    int aoff[4], boff[4];
#pragma unroll
    for (int i = 0; i < 4; ++i) {
        const int r = wr * 64 + i * 16 + (lane & 15);
        aoff[i] = r * 32 + ((kg ^ ((r >> 1) & 3)) * 8);
        const int rw = wc * 64 + i * 16 + (lane & 15);
        boff[i] = BM * 32 + rw * 32 + ((kg ^ ((rw >> 1) & 3)) * 8);
    }

    ffrag acc[4][4];
#pragma unroll
    for (int i = 0; i < 4; ++i)
#pragma unroll
        for (int j = 0; j < 4; ++j) acc[i][j] = (ffrag){0.f, 0.f, 0.f, 0.f};

    const int NT = K >> 5;                 // all call sites have NT >= 8
    // prologue: stage tiles 0,1,2
#pragma unroll
    for (int q = 0; q < 4; ++q) glds16(gsrc[q], ldst[q]);
#pragma unroll
    for (int q = 0; q < 4; ++q) glds16(gsrc[q] + (size_t)gstr[q], ldst[q] + BUF);
#pragma unroll
    for (int q = 0; q < 4; ++q) glds16(gsrc[q] + 2 * (size_t)gstr[q], ldst[q] + 2 * BUF);

    int cur = 0;
    for (int t = 0; t < NT; ++t) {
        if (t + 2 < NT)      asm volatile("s_waitcnt vmcnt(8)" ::: "memory");
        else if (t + 1 < NT) asm volatile("s_waitcnt vmcnt(4)" ::: "memory");
        else                 asm volatile("s_waitcnt vmcnt(0)" ::: "memory");
        __builtin_amdgcn_s_barrier();
        __builtin_amdgcn_sched_barrier(0);

        const ushort_t* Sb = SMu + cur * BUF;
        bfrag af[4], bw[4];
#pragma unroll
        for (int i = 0; i < 4; ++i) af[i] = *(const bfrag*)(Sb + aoff[i]);
#pragma unroll
        for (int j = 0; j < 4; ++j) bw[j] = *(const bfrag*)(Sb + boff[j]);
#pragma unroll
        for (int i = 0; i < 4; ++i)
#pragma unroll
            for (int j = 0; j < 4; ++j)
                acc[i][j] = __builtin_amdgcn_mfma_f32_16x16x32_bf16(
                    af[i], bw[j], acc[i][j], 0, 0, 0);

        __builtin_amdgcn_s_barrier();
        __builtin_amdgcn_sched_barrier(0);
        if (t + 3 < NT) {
#pragma unroll
            for (int q = 0; q < 4; ++q)
                glds16(gsrc[q] + (size_t)(t + 3) * gstr[q], ldst[q] + cur * BUF);
        }
        cur = (cur == 2) ? 0 : cur + 1;
    }

    float bj[4];
#pragma unroll
    for (int j = 0; j < 4; ++j) {
        const int col = n0 + wc * 64 + j * 16 + (lane & 15);
        bj[j] = bias ? bias[col] : 0.0f;
    }

    float* lt = (float*)smem;
    const bool lo = (EPI != 2) || (n0 < DI_);

    for (int i = 0; i < 4; ++i) {            // 32-row chunks
        __syncthreads();
#pragma unroll
        for (int j = 0; j < 4; ++j)
#pragma unroll
            for (int r = 0; r < 4; ++r)
                lt[(wr * 16 + (lane >> 4) * 4 + r) * TP + wc * 64 + j * 16 + (lane & 15)]
                    = acc[i][j][r] + bj[j];
        __syncthreads();
        if (EPI == 1) {
#pragma unroll
            for (int p = 0; p < 2; ++p) {
                const int lrow = p * 16 + (tid >> 4);
                const int cg = tid & 15;
                const int grow = m0 + (lrow >> 4) * 64 + i * 16 + (lrow & 15);
                const int gc = n0 + cg * 8;
                float4 v0 = *(float4*)&lt[lrow * TP + cg * 8];
                float4 v1 = *(float4*)&lt[lrow * TP + cg * 8 + 4];
                float v[8] = { v0.x, v0.y, v0.z, v0.w, v1.x, v1.y, v1.z, v1.w };
                float rv[8];
#pragma unroll
                for (int e = 0; e < 8; ++e) rv[e] = fmaxf(v[e], 0.0f);
                *(uint4*)(C + (size_t)grow * ldc + gc) = pack8(rv);
            }
        } else {
            // kt32 stores: chunk rows = two contiguous 16-runs (64 apart);
            // per ktile the 32x32 block is m-major contiguous in dst.
#pragma unroll
            for (int p = 0; p < 2; ++p) {
                const int slot = p * 256 + tid;       // 0..511
                const int kt = slot >> 7;             // 0..3
                const int rem = slot & 127;
                const int run = rem >> 6, mm = (rem >> 2) & 15, q8 = rem & 3;
                const int lr = run * 16 + mm;
                const int grow = m0 + run * 64 + i * 16 + mm;
                const int colb = n0 + kt * 32 + q8 * 8;
                float4 v0 = *(float4*)&lt[lr * TP + kt * 32 + q8 * 8];
                float4 v1 = *(float4*)&lt[lr * TP + kt * 32 + q8 * 8 + 4];
                float v[8] = { v0.x, v0.y, v0.z, v0.w, v1.x, v1.y, v1.z, v1.w };
                if (EPI == 0) {
                    const size_t dst = (size_t)(colb >> 5) * sC + (size_t)grow * 32 + (colb & 31);
                    *(uint4*)(C + dst) = pack8(v);
                } else {
                    if (lo) {
                        float vf[8], vb[8];
#pragma unroll
                        for (int e = 0; e < 8; ++e) {
                            const int c = colb + e;
                            vf[e] = silu_f(v[e] * cwf[c * 4 + 3] + cbf[c]);
                            vb[e] = silu_f(v[e] * cwb[c * 4 + 3] + cbb[c]);
                        }
                        const size_t dst = (size_t)(colb >> 5) * sC + (size_t)grow * 32 + (colb & 31);
                        *(uint4*)(C + dst)    = pack8(vf);
                        *(uint4*)(out2 + dst) = pack8(vb);
                    } else {
                        float vz[8];
#pragma unroll
                        for (int e = 0; e < 8; ++e) vz[e] = silu_f(v[e]);
                        const int cz = colb - DI_;
                        const size_t dst = (size_t)(cz >> 5) * sC + (size_t)grow * 32 + (cz & 31);
                        *(uint4*)(out3 + dst) = pack8(vz);
                    }
                }
            }
        }
    }
}

// ---------------------------------------------------------------------------
// dbl GEMM 64x64 (K=1024, NT=32), fwd+bwd via blockIdx.y, kt32 operands,
// depth-3 counted pipeline. Stores cols 0..31 (dt_in) row-major [M][32];
// fuses bc[r] = sum_s dbl[r,32+s]*dbl[r,48+s] from f32 acc.
// ---------------------------------------------------------------------------
__global__ __launch_bounds__(256) void dbl_k(
    const ushort_t* __restrict__ Afwd, const ushort_t* __restrict__ Abwd,
    const ushort_t* __restrict__ Wfwd, const ushort_t* __restrict__ Wbwd,
    int sA, int sW,
    ushort_t* __restrict__ Dfwd, ushort_t* __restrict__ Dbwd,
    float* __restrict__ bcFo, float* __restrict__ bcBo)
{
    constexpr int BM = 64, TP = 36;
    constexpr int BUF = 4096;
    __shared__ char smem[24576];
    ushort_t* SMu = (ushort_t*)smem;

    const int tid = threadIdx.x;
    const int lane = tid & 63;
    const int w = tid >> 6;
    const int wr = w >> 1, wc = w & 1;
    const int m0 = blockIdx.x * 64;
    const ushort_t* A = blockIdx.y ? Abwd : Afwd;
    const ushort_t* W = blockIdx.y ? Wbwd : Wfwd;
    ushort_t* D = blockIdx.y ? Dbwd : Dfwd;
    float* bco = blockIdx.y ? bcBo : bcFo;

    const ushort_t* gsrc[2];
    ushort_t* ldst[2];
    int gstr[2];
#pragma unroll
    for (int q = 0; q < 2; ++q) {
        const int lw = w * 2 + q;
        const int c = lw * 64 + lane;
        ldst[q] = SMu + (size_t)lw * 512;
        if (c < BM * 4) {
            const int row = c >> 2, slot = c & 3;
            const int gslot = slot ^ ((row >> 1) & 3);
            gsrc[q] = A + (size_t)(m0 + row) * 32 + gslot * 8;
            gstr[q] = sA;
        } else {
            const int c2 = c - BM * 4;
            const int row = c2 >> 2, slot = c2 & 3;
            const int gslot = slot ^ ((row >> 1) & 3);
            gsrc[q] = W + (size_t)row * 32 + gslot * 8;
            gstr[q] = sW;
        }
    }

    const int kg = lane >> 4;
    int aoff[2], boff[2];
#pragma unroll
    for (int i = 0; i < 2; ++i) {
        const int r = wr * 32 + i * 16 + (lane & 15);
        aoff[i] = r * 32 + ((kg ^ ((r >> 1) & 3)) * 8);
        const int rw = wc * 32 + i * 16 + (lane & 15);
        boff[i] = BM * 32 + rw * 32 + ((kg ^ ((rw >> 1) & 3)) * 8);
    }

    ffrag acc[2][2];
#pragma unroll
    for (int i = 0; i < 2; ++i)
#pragma unroll
        for (int j = 0; j < 2; ++j) acc[i][j] = (ffrag){0.f, 0.f, 0.f, 0.f};

#pragma unroll
    for (int q = 0; q < 2; ++q) glds16(gsrc[q], ldst[q]);
#pragma unroll
    for (int q = 0; q < 2; ++q) glds16(gsrc[q] + (size_t)gstr[q], ldst[q] + BUF);
#pragma unroll
    for (int q = 0; q < 2; ++q) glds16(gsrc[q] + 2 * (size_t)gstr[q], ldst[q] + 2 * BUF);

    int cur = 0;
    for (int t = 0; t < 32; ++t) {
        if (t + 2 < 32)      asm volatile("s_waitcnt vmcnt(4)" ::: "memory");
        else if (t + 1 < 32) asm volatile("s_waitcnt vmcnt(2)" ::: "memory");
        else                 asm volatile("s_waitcnt vmcnt(0)" ::: "memory");
        __builtin_amdgcn_s_barrier();
        __builtin_amdgcn_sched_barrier(0);

        const ushort_t* Sb = SMu + cur * BUF;
        bfrag af[2], bw[2];
#pragma unroll
        for (int i = 0; i < 2; ++i) af[i] = *(const bfrag*)(Sb + aoff[i]);
#pragma unroll
        for (int j = 0; j < 2; ++j) bw[j] = *(const bfrag*)(Sb + boff[j]);
#pragma unroll
        for (int i = 0; i < 2; ++i)
#pragma unroll
            for (int j = 0; j < 2; ++j)
                acc[i][j] = __builtin_amdgcn_mfma_f32_16x16x32_bf16(
                    af[i], bw[j], acc[i][j], 0, 0, 0);

        __builtin_amdgcn_s_barrier();
        __builtin_amdgcn_sched_barrier(0);
        if (t + 3 < 32) {
#pragma unroll
            for (int q = 0; q < 2; ++q)
                glds16(gsrc[q] + (size_t)(t + 3) * gstr[q], ldst[q] + cur * BUF);
        }
        cur = (cur == 2) ? 0 : cur + 1;
    }

    if (wc == 1) {
#pragma unroll
        for (int i = 0; i < 2; ++i)
#pragma unroll
            for (int r = 0; r < 4; ++r) {
                float p = acc[i][0][r] * acc[i][1][r];
                p += __shfl_xor(p, 1, 64);
                p += __shfl_xor(p, 2, 64);
                p += __shfl_xor(p, 4, 64);
                p += __shfl_xor(p, 8, 64);
                if ((lane & 15) == 0)
                    bco[m0 + wr * 32 + i * 16 + (lane >> 4) * 4 + r] = p;
            }
    }

    float* lt = (float*)smem;
    for (int i = 0; i < 2; ++i) {
        __syncthreads();
        if (wc == 0) {
#pragma unroll
            for (int j = 0; j < 2; ++j)
#pragma unroll
                for (int r = 0; r < 4; ++r)
                    lt[(wr * 16 + (lane >> 4) * 4 + r) * TP + j * 16 + (lane & 15)]
                        = acc[i][j][r];
        }
        __syncthreads();
        const int lrow = tid >> 3;      // 0..31
        const int cg = tid & 7;
        if (cg < 4) {
            const int grow = m0 + (lrow >> 4) * 32 + i * 16 + (lrow & 15);
            float4 v0 = *(float4*)&lt[lrow * TP + cg * 8];
            float4 v1 = *(float4*)&lt[lrow * TP + cg * 8 + 4];
            float v[8] = { v0.x, v0.y, v0.z, v0.w, v1.x, v1.y, v1.z, v1.w };
            *(uint4*)(D + (size_t)grow * 32 + cg * 8) = pack8(v);
        }
    }
}

// ---------------------------------------------------------------------------
// dt GEMM (K=32, fwd+bwd) + SSM epilogue. xcf/xcb/szy are kt32; the
// element-wise pass reads/writes contiguous 32-B per thread, 1-KB runs.
//   y = (xcf*(sp(dtf)*bcf + Dpf) + xcb*(sp(dtb)*bcb + Dpb)) * sz  (in-place)
// Block: 128 rows x 64 cols, grid (16, 128).
// ---------------------------------------------------------------------------
__global__ __launch_bounds__(256) void dty_k(
    const ushort_t* __restrict__ dblf, const ushort_t* __restrict__ dblb,
    const ushort_t* __restrict__ wtf,  const ushort_t* __restrict__ wtb,
    const float* __restrict__ dbf, const float* __restrict__ dbb,
    const float* __restrict__ Dpf, const float* __restrict__ Dpb,
    const float* __restrict__ bcf, const float* __restrict__ bcb,
    const ushort_t* __restrict__ xcf, const ushort_t* __restrict__ xcb,
    ushort_t* szy)
{
    __shared__ float ltF[64 * 68];
    __shared__ float ltB[64 * 68];
    const int tid = threadIdx.x, lane = tid & 63, w = tid >> 6;
    const int m0 = blockIdx.y * 128, n0 = blockIdx.x * 64;
    const int koff = (lane >> 4) * 8;

    bfrag aF[2], aB[2], wF[4], wB[4];
#pragma unroll
    for (int i = 0; i < 2; ++i) {
        const int row = m0 + w * 32 + i * 16 + (lane & 15);
        aF[i] = *(const bfrag*)(dblf + (size_t)row * 32 + koff);
        aB[i] = *(const bfrag*)(dblb + (size_t)row * 32 + koff);
    }
#pragma unroll
    for (int j = 0; j < 4; ++j) {
        const int col = n0 + j * 16 + (lane & 15);
        wF[j] = *(const bfrag*)(wtf + (size_t)col * 32 + koff);
        wB[j] = *(const bfrag*)(wtb + (size_t)col * 32 + koff);
    }
    ffrag accF[2][4], accB[2][4];
#pragma unroll
    for (int i = 0; i < 2; ++i)
#pragma unroll
        for (int j = 0; j < 4; ++j) {
            ffrag z = (ffrag){0.f, 0.f, 0.f, 0.f};
            accF[i][j] = __builtin_amdgcn_mfma_f32_16x16x32_bf16(aF[i], wF[j], z, 0, 0, 0);
            z = (ffrag){0.f, 0.f, 0.f, 0.f};
            accB[i][j] = __builtin_amdgcn_mfma_f32_16x16x32_bf16(aB[i], wB[j], z, 0, 0, 0);
        }

    float dbfj[4], dbbj[4];
#pragma unroll
    for (int j = 0; j < 4; ++j) {
        const int c = n0 + j * 16 + (lane & 15);
        dbfj[j] = dbf[c]; dbbj[j] = dbb[c];
    }

    for (int i = 0; i < 2; ++i) {
        __syncthreads();
#pragma unroll
        for (int j = 0; j < 4; ++j)
#pragma unroll
            for (int r = 0; r < 4; ++r) {
                const int lr = w * 16 + (lane >> 4) * 4 + r;
                const int cc = j * 16 + (lane & 15);
                ltF[lr * 68 + cc] = accF[i][j][r] + dbfj[j];
                ltB[lr * 68 + cc] = accB[i][j][r] + dbbj[j];
            }
        __syncthreads();
        // rows in lt: 4 runs of 16 (stride 32); cols 64 = 2 ktiles.
        const int kt2 = tid >> 7;             // 0..1
        const int rem = tid & 127;
        const int run = rem >> 5, mm = (rem >> 1) & 15, q16 = rem & 1;
        const int lr = run * 16 + mm;
        const int grow = m0 + run * 32 + i * 16 + mm;
        const int col0 = n0 + kt2 * 32 + q16 * 16;
        const size_t base = (size_t)(col0 >> 5) * SKT + (size_t)grow * 32 + (col0 & 31);
        const float vbcf = bcf[grow], vbcb = bcb[grow];
        union { uint4 u[2]; ushort_t s[16]; } xf, xb, sz;
        xf.u[0] = *(const uint4*)(xcf + base); xf.u[1] = *(const uint4*)(xcf + base + 8);
        xb.u[0] = *(const uint4*)(xcb + base); xb.u[1] = *(const uint4*)(xcb + base + 8);
        sz.u[0] = *(const uint4*)(szy + base); sz.u[1] = *(const uint4*)(szy + base + 8);
        float v[16];
#pragma unroll
        for (int e = 0; e < 16; ++e) {
            const int cc = kt2 * 32 + q16 * 16 + e;
            const float dtf = softplus_f(ltF[lr * 68 + cc]);
            const float dtb = softplus_f(ltB[lr * 68 + cc]);
            const float vf = us2f(xf.s[e]) * (dtf * vbcf + Dpf[col0 + e]);
            const float vb = us2f(xb.s[e]) * (dtb * vbcb + Dpb[col0 + e]);
            v[e] = (vf + vb) * us2f(sz.s[e]);
        }
        *(uint4*)(szy + base)     = pack8(v);
        *(uint4*)(szy + base + 8) = pack8(v + 8);
    }
}

// ---------------------------------------------------------------------------
// Modality fusion: 4 tokens/block, wave per token; h written kt32 via LDS.
// ---------------------------------------------------------------------------
__global__ __launch_bounds__(256) void fuseh_k(
    const ushort_t* __restrict__ r0, const ushort_t* __restrict__ r1,
    const ushort_t* __restrict__ r2, ushort_t* __restrict__ h)
{
    __shared__ ushort_t ls[4][512];
    const int tok = threadIdx.x >> 6;
    const int lane = threadIdx.x & 63;
    const int t = blockIdx.x * 4 + tok;
    uint4 raw0 = *(const uint4*)(r0 + (size_t)t * 512 + lane * 8);
    uint4 raw1 = *(const uint4*)(r1 + (size_t)t * 512 + lane * 8);
    uint4 raw2 = *(const uint4*)(r2 + (size_t)t * 512 + lane * 8);
    const ushort_t* p0 = (const ushort_t*)&raw0;
    const ushort_t* p1 = (const ushort_t*)&raw1;
    const ushort_t* p2 = (const ushort_t*)&raw2;
    float v0[8], v1[8], v2[8];
    float s0 = 0.f, s1 = 0.f, s2 = 0.f;
#pragma unroll
    for (int j = 0; j < 8; ++j) {
        v0[j] = us2f(p0[j]); v1[j] = us2f(p1[j]); v2[j] = us2f(p2[j]);
        s0 += v0[j] * v0[j]; s1 += v1[j] * v1[j]; s2 += v2[j] * v2[j];
    }
#pragma unroll
    for (int m = 32; m >= 1; m >>= 1) {
        s0 += __shfl_xor(s0, m, 64);
        s1 += __shfl_xor(s1, m, 64);
        s2 += __shfl_xor(s2, m, 64);
    }
    const float n0 = sqrtf(s0), n1 = sqrtf(s1), n2 = sqrtf(s2);
    const float mx = fmaxf(n0, fmaxf(n1, n2));
    const float e0 = __expf(n0 - mx), e1 = __expf(n1 - mx), e2 = __expf(n2 - mx);
    const float inv = __builtin_amdgcn_rcpf(e0 + e1 + e2);
    const float w0 = e0 * inv / fmaxf(n0, 1e-12f);
    const float w1 = e1 * inv / fmaxf(n1, 1e-12f);
    const float w2 = e2 * inv / fmaxf(n2, 1e-12f);
    float o[8];
#pragma unroll
    for (int j = 0; j < 8; ++j) o[j] = w0 * v0[j] + w1 * v1[j] + w2 * v2[j];
    *(uint4*)&ls[tok][lane * 8] = pack8(o);
    __syncthreads();
    // kt32 store: 16 ktiles x (4 tok x 4 q8) -> 256-B contiguous runs/ktile
    const int kt = threadIdx.x >> 4;
    const int s = threadIdx.x & 15;
    const int tk = s >> 2, q8 = s & 3;
    uint4 val = *(uint4*)&ls[tk][kt * 32 + q8 * 8];
    *(uint4*)(h + (size_t)kt * SKT + (size_t)(blockIdx.x * 4 + tk) * 32 + q8 * 8) = val;
}

// ---------------------------------------------------------------------------
// Head: logits = tanh(hid @ fc2^T + b), log_softmax(2). OUTPUT FLOAT32.
// ---------------------------------------------------------------------------
__global__ __launch_bounds__(256) void head_k(
    const ushort_t* __restrict__ hid, const float* __restrict__ fc2w,
    const float* __restrict__ fc2b, float* __restrict__ out)
{
    const int tid = threadIdx.x;
    const int lane = tid & 63;
    const int t = blockIdx.x * 4 + (tid >> 6);
    uint2 raw = *(const uint2*)(hid + (size_t)t * 256 + lane * 4);
    const ushort_t* hp = (const ushort_t*)&raw;
    float4 w0 = *(const float4*)(fc2w + lane * 4);
    float4 w1 = *(const float4*)(fc2w + 256 + lane * 4);
    float h0 = us2f(hp[0]), h1 = us2f(hp[1]), h2 = us2f(hp[2]), h3 = us2f(hp[3]);
    float d0 = h0 * w0.x + h1 * w0.y + h2 * w0.z + h3 * w0.w;
    float d1 = h0 * w1.x + h1 * w1.y + h2 * w1.z + h3 * w1.w;
#pragma unroll
    for (int m = 32; m >= 1; m >>= 1) {
        d0 += __shfl_xor(d0, m, 64);
        d1 += __shfl_xor(d1, m, 64);
    }
    if (lane == 0) {
        const float l0 = tanhf(d0 + fc2b[0]);
        const float l1 = tanhf(d1 + fc2b[1]);
        const float mx = fmaxf(l0, l1);
        const float lse = mx + __logf(__expf(l0 - mx) + __expf(l1 - mx));
        out[(size_t)t * 2 + 0] = l0 - lse;
        out[(size_t)t * 2 + 1] = l1 - lse;
    }
}

// ---------------------------------------------------------------------------
extern "C" void kernel_launch(void* const* d_in, const int* in_sizes, int n_in,
                              void* d_out, int out_size, void* d_ws, size_t ws_size,
                              hipStream_t stream)
{
    const float* text    = (const float*)d_in[0];
    const float* audio   = (const float*)d_in[1];
    const float* visual  = (const float*)d_in[3];
    const float* W_text  = (const float*)d_in[4];
    const float* b_text  = (const float*)d_in[5];
    const float* W_audio = (const float*)d_in[6];
    const float* b_audio = (const float*)d_in[7];
    const float* W_vis   = (const float*)d_in[8];
    const float* b_vis   = (const float*)d_in[9];
    const float* in_w    = (const float*)d_in[10];
    const float* in_b    = (const float*)d_in[11];
    const float* conv_w  = (const float*)d_in[12];
    const float* conv_b  = (const float*)d_in[13];
    const float* xproj_w = (const float*)d_in[14];
    const float* dt_w    = (const float*)d_in[15];
    const float* dt_b    = (const float*)d_in[16];
    const float* Dskip   = (const float*)d_in[17];
    const float* conv_wB = (const float*)d_in[18];
    const float* conv_bB = (const float*)d_in[19];
    const float* xprojB  = (const float*)d_in[20];
    const float* dt_wB   = (const float*)d_in[21];
    const float* dt_bB   = (const float*)d_in[22];
    const float* DskipB  = (const float*)d_in[23];
    const float* out_w   = (const float*)d_in[24];
    const float* out_b   = (const float*)d_in[25];
    const float* fc1_w   = (const float*)d_in[26];
    const float* fc1_b   = (const float*)d_in[27];
    const float* fc2_w   = (const float*)d_in[28];
    const float* fc2_b   = (const float*)d_in[29];
    float* out           = (float*)d_out;

    // ---- workspace carve (all kt32 unless noted) ----
    ushort_t* wsu = (ushort_t*)d_ws;
    size_t off = 0;
    auto alloc = [&](size_t n) { ushort_t* p = wsu + off; off += n; return p; };
    ushort_t* t_bf   = alloc(12582912);   // text kt32 (M=16384,K=768)
    ushort_t* a_bf   = alloc(8388608);
    ushort_t* v_bf   = alloc(4194304);
    ushort_t* Wt_bf  = alloc(393216);     // kt32 R=512
    ushort_t* Wa_bf  = alloc(262144);
    ushort_t* Wv_bf  = alloc(131072);
    ushort_t* inw_bf = alloc(2097152);    // kt32 R=4096 (layers stacked), K=512
    ushort_t* xpf_bf = alloc(131072);     // kt32 R=128, K=1024
    ushort_t* dwf_bf = alloc(65536);      // plain [2][1024][32]
    ushort_t* xpb_bf = alloc(131072);
    ushort_t* dwb_bf = alloc(65536);
    ushort_t* ow_bf  = alloc(1048576);    // kt32 R=1024, K=1024
    ushort_t* f1_bf  = alloc(131072);     // kt32 R=256, K=512
    ushort_t* b_h    = alloc(8388608);    // kt32 [16][M][32]
    ushort_t* b_xcf  = alloc(16777216);   // kt32 [32][M][32]
    ushort_t* b_xcb  = alloc(16777216);
    ushort_t* b_szy  = alloc(16777216);   // kt32; silu(z) then y in-place
    ushort_t* b_dblf = alloc(524288);     // row-major [M][32]
    ushort_t* b_dblb = alloc(524288);
    ushort_t* b_hid  = alloc(4194304);    // row-major [M][256]
    float* b_bcf = (float*)(wsu + off); off += 2 * MTOT;
    float* b_bcb = (float*)(wsu + off); off += 2 * MTOT;
    (void)ws_size;

    // ---- conversions (kt32 where GEMM-consumed) ----
    CvtArgs ca;
    const float* srcs[13] = { text, audio, visual, W_text, W_audio, W_vis,
                              in_w, xproj_w, dt_w, xprojB, dt_wB, out_w, fc1_w };
    ushort_t* dsts[13] = { t_bf, a_bf, v_bf, Wt_bf, Wa_bf, Wv_bf,
                           inw_bf, xpf_bf, dwf_bf, xpb_bf, dwb_bf, ow_bf, f1_bf };
    const int ns[13]  = { 12582912, 8388608, 4194304, 393216, 262144, 131072,
                          2097152, 131072, 65536, 131072, 65536, 1048576, 131072 };
    const int kqs[13] = { 192, 128, 64, 192, 128, 64, 128, 256, 0, 256, 0, 256, 128 };
    const int r32s[13]= { 524288, 524288, 524288, 16384, 16384, 16384,
                          131072, 4096, 0, 4096, 0, 32768, 8192 };
    for (int i = 0; i < 13; ++i) {
        ca.src[i] = srcs[i]; ca.dst[i] = dsts[i];
        ca.n[i] = ns[i]; ca.kq[i] = kqs[i]; ca.r32[i] = r32s[i];
    }
    cvt_k<<<dim3(192, 13), 256, 0, stream>>>(ca);

    const dim3 blk(256);
    const int sM = (int)SKT;   // 524288
    // modality projections (relu, row-major reps staged in xcf/xcb/szy)
    mgemm_k<1><<<dim3(4, 128), blk, 0, stream>>>(
        t_bf, sM, Wt_bf, 512 * 32, b_text, b_xcf, 512, 0, 768,
        nullptr, nullptr, nullptr, nullptr, nullptr, nullptr);
    mgemm_k<1><<<dim3(4, 128), blk, 0, stream>>>(
        a_bf, sM, Wa_bf, 512 * 32, b_audio, b_xcb, 512, 0, 512,
        nullptr, nullptr, nullptr, nullptr, nullptr, nullptr);
    mgemm_k<1><<<dim3(4, 128), blk, 0, stream>>>(
        v_bf, sM, Wv_bf, 512 * 32, b_vis, b_szy, 512, 0, 256,
        nullptr, nullptr, nullptr, nullptr, nullptr, nullptr);
    fuseh_k<<<MTOT / 4, blk, 0, stream>>>(b_xcf, b_xcb, b_szy, b_h);

    for (int l = 0; l < 2; ++l) {
        mgemm_k<2><<<dim3(16, 128), blk, 0, stream>>>(
            b_h, sM, inw_bf + (size_t)l * 2048 * 32, 4096 * 32, in_b + l * 2048,
            b_xcf, 0, sM, 512,
            conv_w + l * 4096, conv_b + l * 1024,
            conv_wB + l * 4096, conv_bB + l * 1024, b_xcb, b_szy);
        dbl_k<<<dim3(256, 2), blk, 0, stream>>>(
            b_xcf, b_xcb,
            xpf_bf + (size_t)l * 64 * 32, xpb_bf + (size_t)l * 64 * 32,
            sM, 128 * 32,
            b_dblf, b_dblb, b_bcf, b_bcb);
        dty_k<<<dim3(16, 128), blk, 0, stream>>>(
            b_dblf, b_dblb,
            dwf_bf + (size_t)l * 32768, dwb_bf + (size_t)l * 32768,
            dt_b + l * 1024, dt_bB + l * 1024,
            Dskip + l * 1024, DskipB + l * 1024,
            b_bcf, b_bcb, b_xcf, b_xcb, b_szy);
        mgemm_k<0><<<dim3(4, 128), blk, 0, stream>>>(
            b_szy, sM, ow_bf + (size_t)l * 512 * 32, 1024 * 32, out_b + l * 512,
            b_h, 0, sM, 1024,
            nullptr, nullptr, nullptr, nullptr, nullptr, nullptr);
    }

    mgemm_k<1><<<dim3(2, 128), blk, 0, stream>>>(
        b_h, sM, f1_bf, 256 * 32, fc1_b, b_hid, 256, 0, 512,
        nullptr, nullptr, nullptr, nullptr, nullptr, nullptr);
    head_k<<<MTOT / 4, blk, 0, stream>>>(b_hid, fc2_w, fc2_b, out);
}